// Round 1
// baseline (1743.673 us; speedup 1.0000x reference)
//
#include <hip/hip_runtime.h>
#include <math.h>

#define NN 25000
#define EE 400000
#define LL 3
#define LNEPS 1e-5f
#define GROWS 32
#define EB 64

__device__ __forceinline__ float lrelu(float x, float s) { return x >= 0.f ? x : s * x; }

__device__ __forceinline__ unsigned int pack_bf2(float lo, float hi) {
    unsigned int ul = __float_as_uint(lo), uh = __float_as_uint(hi);
    ul = (ul + 0x7FFFu + ((ul >> 16) & 1u)) >> 16;
    uh = (uh + 0x7FFFu + ((uh >> 16) & 1u)) >> 16;
    return (uh << 16) | (ul & 0xFFFFu);
}
__device__ __forceinline__ float bf_lo(unsigned int u) { return __uint_as_float(u << 16); }
__device__ __forceinline__ float bf_hi(unsigned int u) { return __uint_as_float(u & 0xFFFF0000u); }

// 128-thread block LN stats (2 waves)
__device__ __forceinline__ void ln_stats128(float v, float* red, float& mean, float& inv) {
    float sm = v, sq = v * v;
#pragma unroll
    for (int m = 32; m >= 1; m >>= 1) { sm += __shfl_xor(sm, m); sq += __shfl_xor(sq, m); }
    __syncthreads();
    if ((threadIdx.x & 63) == 0) { red[(threadIdx.x >> 6) * 2] = sm; red[(threadIdx.x >> 6) * 2 + 1] = sq; }
    __syncthreads();
    sm = red[0] + red[2]; sq = red[1] + red[3];
    mean = sm * (1.f / 128.f);
    float var = sq * (1.f / 128.f) - mean * mean;
    inv = rsqrtf(var + LNEPS);
}

// ---- node GEMM: out[n,128] = (opt LN+lrelu)(in[n,128] @ W[128,128] (+bias)) ----
__global__ __launch_bounds__(256) void k_node_gemm(
    const float* __restrict__ in, const float* __restrict__ W,
    const float* __restrict__ bias, const float* __restrict__ g,
    const float* __restrict__ be, float* __restrict__ out,
    float* __restrict__ out2, int nrows, int do_ln, float slope)
{
    __shared__ float sW[128 * 128];
    __shared__ float sIn[GROWS * 128];
    const int tid = threadIdx.x;
    {
        const float4* W4 = (const float4*)W;
        float4* sW4 = (float4*)sW;
#pragma unroll
        for (int i = 0; i < 16; ++i) sW4[tid + 256 * i] = W4[tid + 256 * i];
    }
    const int r0 = blockIdx.x * GROWS;
    {
        const float4* in4 = (const float4*)in;
        float4* sIn4 = (float4*)sIn;
#pragma unroll
        for (int i = 0; i < 4; ++i) {
            int idx = tid + 256 * i;
            int row = idx >> 5;
            sIn4[idx] = (r0 + row < nrows) ? in4[(size_t)r0 * 32 + idx]
                                           : make_float4(0.f, 0.f, 0.f, 0.f);
        }
    }
    __syncthreads();
    const int rt = tid >> 5, ct = tid & 31;
    float acc[4][4];
#pragma unroll
    for (int i = 0; i < 4; ++i) acc[i][0] = acc[i][1] = acc[i][2] = acc[i][3] = 0.f;
#pragma unroll 4
    for (int k = 0; k < 128; ++k) {
        float4 wv = *(const float4*)&sW[k * 128 + ct * 4];
#pragma unroll
        for (int i = 0; i < 4; ++i) {
            float a = sIn[(rt * 4 + i) * 128 + k];
            acc[i][0] += a * wv.x; acc[i][1] += a * wv.y;
            acc[i][2] += a * wv.z; acc[i][3] += a * wv.w;
        }
    }
    if (!do_ln) {
#pragma unroll
        for (int i = 0; i < 4; ++i) {
            int row = r0 + rt * 4 + i;
            if (row < nrows)
                *(float4*)&out[(size_t)row * 128 + ct * 4] =
                    make_float4(acc[i][0], acc[i][1], acc[i][2], acc[i][3]);
        }
    } else {
        float4 bv = *(const float4*)&bias[ct * 4];
        float4 gv = *(const float4*)&g[ct * 4];
        float4 ev = *(const float4*)&be[ct * 4];
        float rs[4], rq[4];
#pragma unroll
        for (int i = 0; i < 4; ++i) {
            acc[i][0] += bv.x; acc[i][1] += bv.y; acc[i][2] += bv.z; acc[i][3] += bv.w;
            rs[i] = acc[i][0] + acc[i][1] + acc[i][2] + acc[i][3];
            rq[i] = acc[i][0] * acc[i][0] + acc[i][1] * acc[i][1]
                  + acc[i][2] * acc[i][2] + acc[i][3] * acc[i][3];
        }
#pragma unroll
        for (int m = 16; m >= 1; m >>= 1) {
#pragma unroll
            for (int i = 0; i < 4; ++i) { rs[i] += __shfl_xor(rs[i], m); rq[i] += __shfl_xor(rq[i], m); }
        }
#pragma unroll
        for (int i = 0; i < 4; ++i) {
            int row = r0 + rt * 4 + i;
            float mean = rs[i] * (1.f / 128.f);
            float var = rq[i] * (1.f / 128.f) - mean * mean;
            float inv = rsqrtf(var + LNEPS);
            float4 o;
            o.x = lrelu((acc[i][0] - mean) * inv * gv.x + ev.x, slope);
            o.y = lrelu((acc[i][1] - mean) * inv * gv.y + ev.y, slope);
            o.z = lrelu((acc[i][2] - mean) * inv * gv.z + ev.z, slope);
            o.w = lrelu((acc[i][3] - mean) * inv * gv.w + ev.w, slope);
            if (row < nrows) {
                *(float4*)&out[(size_t)row * 128 + ct * 4] = o;
                if (out2) *(float4*)&out2[(size_t)row * 128 + ct * 4] = o;
            }
        }
    }
}

// ---- GAT attention scores a_s, a_d  [N,2] ----
__global__ void k_gat_scores(const float* __restrict__ ht, const float* __restrict__ as_,
                             const float* __restrict__ ad_, float* __restrict__ a_s,
                             float* __restrict__ a_d, int n)
{
    int idx = blockIdx.x * blockDim.x + threadIdx.x;
    if (idx >= n * 2) return;
    int node = idx >> 1, hd = idx & 1;
    const float4* row = (const float4*)(ht + (size_t)node * 128 + hd * 64);
    const float4* wsv = (const float4*)(as_ + hd * 64);
    const float4* wdv = (const float4*)(ad_ + hd * 64);
    float ss = 0.f, sd = 0.f;
#pragma unroll
    for (int i = 0; i < 16; ++i) {
        float4 v = row[i], vs = wsv[i], vd = wdv[i];
        ss += v.x * vs.x + v.y * vs.y + v.z * vs.z + v.w * vs.w;
        sd += v.x * vd.x + v.y * vd.y + v.z * vd.z + v.w * vd.w;
    }
    a_s[idx] = ss; a_d[idx] = sd;
}

// ---- denom init with self-loop term ----
__global__ void k_denom_init(const float* __restrict__ a_s, const float* __restrict__ a_d,
                             float* __restrict__ denom, int n)
{
    int idx = blockIdx.x * blockDim.x + threadIdx.x;
    if (idx >= n * 2) return;
    float e = lrelu(a_s[idx] + a_d[idx], 0.2f);
    denom[idx] = expf(e);
}

// ---- accumulate exp(e) per dst over edges ----
__global__ void k_edge_denom(const int* __restrict__ src, const int* __restrict__ dst,
                             const float* __restrict__ a_s, const float* __restrict__ a_d,
                             float* __restrict__ denom, int ne)
{
    int idx = blockIdx.x * blockDim.x + threadIdx.x;
    if (idx >= ne * 2) return;
    int e = idx >> 1, hd = idx & 1;
    int s = src[e], d = dst[e];
    float ev = lrelu(a_s[s * 2 + hd] + a_d[d * 2 + hd], 0.2f);
    atomicAdd(&denom[d * 2 + hd], expf(ev));
}

// ---- xsum = gat_bias + self-loop GAT contribution ----
__global__ void k_xsum_init(const float* __restrict__ ht, const float* __restrict__ a_s,
                            const float* __restrict__ a_d, const float* __restrict__ denom,
                            const float* __restrict__ gbias, float* __restrict__ xsum, int n)
{
    int idx = blockIdx.x * blockDim.x + threadIdx.x;
    if (idx >= n * 128) return;
    int node = idx >> 7, c = idx & 127, hd = c >> 6;
    float es = lrelu(a_s[node * 2 + hd] + a_d[node * 2 + hd], 0.2f);
    float alpha = expf(es) / denom[node * 2 + hd];
    xsum[idx] = gbias[c] + ht[idx] * alpha;
}

// ---- fused edge kernel: EdgeConv MLP (factored A+B) + GAT scatter ----
__global__ __launch_bounds__(512) void k_edge_main(
    const float* __restrict__ Abuf, const float* __restrict__ Bbuf,
    const float* __restrict__ ht,
    const int* __restrict__ src, const int* __restrict__ dst,
    const float* __restrict__ ea,
    const float* __restrict__ a_s, const float* __restrict__ a_d,
    const float* __restrict__ denom,
    const float* __restrict__ W2,
    const float* __restrict__ b1, const float* __restrict__ g1, const float* __restrict__ be1,
    const float* __restrict__ b2, const float* __restrict__ g2, const float* __restrict__ be2,
    float* __restrict__ xsum, int ne)
{
    __shared__ __align__(16) unsigned int sW32[128 * 64];  // W2 as bf16 pairs, 32KB
    __shared__ __align__(16) unsigned int sT32[EB * 64];   // t / u tile as bf16 pairs, 16KB
    __shared__ int   sS[EB], sD[EB];
    __shared__ float sEA[EB];
    __shared__ float sAl[EB * 2];
    __shared__ float sB1[128], sG1[128], sE1[128], sB2[128], sG2[128], sE2[128];

    const int tid = threadIdx.x;
    {   // stage W2 -> bf16 in LDS
        const float4* W4 = (const float4*)W2;
        uint2* sWu = (uint2*)sW32;
#pragma unroll
        for (int i = 0; i < 8; ++i) {
            int f = tid + 512 * i;
            float4 w = W4[f];
            sWu[f] = make_uint2(pack_bf2(w.x, w.y), pack_bf2(w.z, w.w));
        }
    }
    if (tid < 128) {
        sB1[tid] = b1[tid]; sG1[tid] = g1[tid]; sE1[tid] = be1[tid];
        sB2[tid] = b2[tid]; sG2[tid] = g2[tid]; sE2[tid] = be2[tid];
    }
    const int e0 = blockIdx.x * EB;
    const int nev = (ne - e0 < EB) ? (ne - e0) : EB;
    if (tid < EB) {
        if (tid < nev) { sS[tid] = src[e0 + tid]; sD[tid] = dst[e0 + tid]; sEA[tid] = ea[e0 + tid]; }
        else           { sS[tid] = 0; sD[tid] = 0; sEA[tid] = 0.f; }
    }
    if (tid < 2 * EB) {
        int le = tid >> 1, hd = tid & 1;
        float al = 0.f;
        if (le < nev) {
            int e = e0 + le;
            int s = src[e], d = dst[e];
            float ev = lrelu(a_s[s * 2 + hd] + a_d[d * 2 + hd], 0.2f);
            al = expf(ev) / denom[d * 2 + hd];
        }
        sAl[le * 2 + hd] = al;
    }
    __syncthreads();

    // phase 1: t = lrelu(LN(A[src]+B[dst]+b1), 0.2) -> bf16 LDS
    const int wv = tid >> 6, ln = tid & 63;
    for (int j = 0; j < 8; ++j) {
        int e = wv * 8 + j;
        if (e < nev) {
            int s = sS[e], d = sD[e];
            float2 av = *(const float2*)&Abuf[(size_t)s * 128 + ln * 2];
            float2 bv = *(const float2*)&Bbuf[(size_t)d * 128 + ln * 2];
            float v0 = av.x + bv.x + sB1[ln * 2];
            float v1 = av.y + bv.y + sB1[ln * 2 + 1];
            float sm = v0 + v1, sq = v0 * v0 + v1 * v1;
#pragma unroll
            for (int m = 32; m >= 1; m >>= 1) { sm += __shfl_xor(sm, m); sq += __shfl_xor(sq, m); }
            float mean = sm * (1.f / 128.f);
            float var = sq * (1.f / 128.f) - mean * mean;
            float inv = rsqrtf(var + LNEPS);
            v0 = lrelu((v0 - mean) * inv * sG1[ln * 2] + sE1[ln * 2], 0.2f);
            v1 = lrelu((v1 - mean) * inv * sG1[ln * 2 + 1] + sE1[ln * 2 + 1], 0.2f);
            sT32[e * 64 + ln] = pack_bf2(v0, v1);
        }
    }
    __syncthreads();

    // phase 2: u = t @ W2  (fp32 accumulate over bf16 operands)
    const int rt = tid >> 5, ct = tid & 31;
    float acc[4][4];
#pragma unroll
    for (int i = 0; i < 4; ++i) acc[i][0] = acc[i][1] = acc[i][2] = acc[i][3] = 0.f;
#pragma unroll 2
    for (int k2 = 0; k2 < 64; ++k2) {
        uint2 wp0 = *(const uint2*)&sW32[(2 * k2) * 64 + ct * 2];
        uint2 wp1 = *(const uint2*)&sW32[(2 * k2 + 1) * 64 + ct * 2];
        float w00 = bf_lo(wp0.x), w01 = bf_hi(wp0.x), w02 = bf_lo(wp0.y), w03 = bf_hi(wp0.y);
        float w10 = bf_lo(wp1.x), w11 = bf_hi(wp1.x), w12 = bf_lo(wp1.y), w13 = bf_hi(wp1.y);
#pragma unroll
        for (int i = 0; i < 4; ++i) {
            unsigned int ap = sT32[(rt * 4 + i) * 64 + k2];
            float a0 = bf_lo(ap), a1 = bf_hi(ap);
            acc[i][0] += a0 * w00; acc[i][1] += a0 * w01; acc[i][2] += a0 * w02; acc[i][3] += a0 * w03;
            acc[i][0] += a1 * w10; acc[i][1] += a1 * w11; acc[i][2] += a1 * w12; acc[i][3] += a1 * w13;
        }
    }
    __syncthreads();
    // write u (+b2) back to sT32
    {
        float4 b2v = *(const float4*)&sB2[ct * 4];
#pragma unroll
        for (int i = 0; i < 4; ++i) {
            int row = rt * 4 + i;
            sT32[row * 64 + ct * 2]     = pack_bf2(acc[i][0] + b2v.x, acc[i][1] + b2v.y);
            sT32[row * 64 + ct * 2 + 1] = pack_bf2(acc[i][2] + b2v.z, acc[i][3] + b2v.w);
        }
    }
    __syncthreads();

    // phase 3: LN(u)+lrelu, *edge_attr, + GAT ht[src]*alpha, atomic scatter to xsum[dst]
    for (int j = 0; j < 8; ++j) {
        int e = wv * 8 + j;
        if (e < nev) {
            int s = sS[e], d = sD[e];
            unsigned int up = sT32[e * 64 + ln];
            float u0 = bf_lo(up), u1 = bf_hi(up);
            float sm = u0 + u1, sq = u0 * u0 + u1 * u1;
#pragma unroll
            for (int m = 32; m >= 1; m >>= 1) { sm += __shfl_xor(sm, m); sq += __shfl_xor(sq, m); }
            float mean = sm * (1.f / 128.f);
            float var = sq * (1.f / 128.f) - mean * mean;
            float inv = rsqrtf(var + LNEPS);
            float eav = sEA[e];
            float v0 = lrelu((u0 - mean) * inv * sG2[ln * 2] + sE2[ln * 2], 0.2f) * eav;
            float v1 = lrelu((u1 - mean) * inv * sG2[ln * 2 + 1] + sE2[ln * 2 + 1], 0.2f) * eav;
            float al = sAl[e * 2 + (ln >> 5)];
            float2 hv = *(const float2*)&ht[(size_t)s * 128 + ln * 2];
            v0 += hv.x * al;
            v1 += hv.y * al;
            atomicAdd(&xsum[(size_t)d * 128 + ln * 2], v0);
            atomicAdd(&xsum[(size_t)d * 128 + ln * 2 + 1], v1);
        }
    }
}

// ---- h = lrelu(LN(xsum)) (+ x0 residual, update x0) ----
__global__ __launch_bounds__(128) void k_norm(const float* __restrict__ xsum,
                                              const float* __restrict__ g,
                                              const float* __restrict__ b,
                                              float* __restrict__ x0,
                                              float* __restrict__ h, int n, int layer)
{
    __shared__ float red[4];
    int node = blockIdx.x, c = threadIdx.x;
    float v = xsum[(size_t)node * 128 + c];
    float mean, inv;
    ln_stats128(v, red, mean, inv);
    float val = lrelu((v - mean) * inv * g[c] + b[c], 0.01f);
    if (layer > 0) {
        val += x0[(size_t)node * 128 + c];
        x0[(size_t)node * 128 + c] = val;
    }
    h[(size_t)node * 128 + c] = val;
}

// ---- pooling attention scores (one node per wave) ----
__global__ __launch_bounds__(256) void k_pool_score(const float* __restrict__ h,
    const float* __restrict__ w1, const float* __restrict__ b1,
    const float* __restrict__ w2, const float* __restrict__ b2,
    float* __restrict__ score, int n)
{
    int wv = threadIdx.x >> 6, ln = threadIdx.x & 63;
    int node = blockIdx.x * 4 + wv;
    if (node >= n) return;
    float acc = b1[ln];
    const float* hr = h + (size_t)node * 128;
    for (int k = 0; k < 128; ++k) acc += hr[k] * w1[k * 64 + ln];
    acc = lrelu(acc, 0.01f) * w2[ln];
#pragma unroll
    for (int m = 32; m >= 1; m >>= 1) acc += __shfl_xor(acc, m);
    if (ln == 0) score[node] = acc + b2[0];
}

// ---- softmax stats (single block) + zero gf ----
__global__ __launch_bounds__(256) void k_softmax_reduce(const float* __restrict__ score,
                                                        float* __restrict__ stats,
                                                        float* __restrict__ gf, int n)
{
    __shared__ float red[8];
    int t = threadIdx.x;
    float mx = -1e30f;
    for (int i = t; i < n; i += 256) mx = fmaxf(mx, score[i]);
#pragma unroll
    for (int m = 32; m >= 1; m >>= 1) mx = fmaxf(mx, __shfl_xor(mx, m));
    if ((t & 63) == 0) red[t >> 6] = mx;
    __syncthreads();
    mx = fmaxf(fmaxf(red[0], red[1]), fmaxf(red[2], red[3]));
    float s = 0.f;
    for (int i = t; i < n; i += 256) s += expf(score[i] - mx);
#pragma unroll
    for (int m = 32; m >= 1; m >>= 1) s += __shfl_xor(s, m);
    if ((t & 63) == 0) red[4 + (t >> 6)] = s;
    __syncthreads();
    s = red[4] + red[5] + red[6] + red[7];
    if (t == 0) { stats[0] = mx; stats[1] = s; }
    if (t < 128) gf[t] = 0.f;
}

// ---- gf = sum_n softmax(score)[n] * h[n,:] ----
__global__ __launch_bounds__(128) void k_gf(const float* __restrict__ h,
                                            const float* __restrict__ score,
                                            const float* __restrict__ stats,
                                            float* __restrict__ gf, int n)
{
    int c = threadIdx.x;
    float mx = stats[0], invZ = 1.f / stats[1];
    int per = (n + gridDim.x - 1) / gridDim.x;
    int n0 = blockIdx.x * per;
    int n1 = n0 + per; if (n1 > n) n1 = n;
    float acc = 0.f;
    for (int i = n0; i < n1; ++i)
        acc += expf(score[i] - mx) * invZ * h[(size_t)i * 128 + c];
    atomicAdd(&gf[c], acc);
}

// ---- final head (single 128-thread block) ----
__global__ __launch_bounds__(128) void k_head(
    const float* __restrict__ gf, const float* __restrict__ tf,
    const float* __restrict__ task_w, const float* __restrict__ task_b,
    const float* __restrict__ task_g, const float* __restrict__ task_be,
    const float* __restrict__ v_w1, const float* __restrict__ v_b1,
    const float* __restrict__ v_g, const float* __restrict__ v_be,
    const float* __restrict__ v_w2, const float* __restrict__ v_b2,
    const float* __restrict__ a_w1, const float* __restrict__ a_b1,
    const float* __restrict__ a_g, const float* __restrict__ a_be,
    const float* __restrict__ a_w2, const float* __restrict__ a_b2,
    float* __restrict__ out)
{
    __shared__ float cf[256], hbuf[128], red[4], sc[2], adv[10];
    int t = threadIdx.x;
    float mean, inv;
    // task embedding
    float te = task_b[t];
#pragma unroll
    for (int k = 0; k < 4; ++k) te += tf[k] * task_w[k * 128 + t];
    ln_stats128(te, red, mean, inv);
    te = lrelu((te - mean) * inv * task_g[t] + task_be[t], 0.01f);
    cf[t] = gf[t]; cf[128 + t] = te;
    __syncthreads();
    // value branch
    float v = v_b1[t];
    for (int k = 0; k < 256; ++k) v += cf[k] * v_w1[k * 128 + t];
    ln_stats128(v, red, mean, inv);
    v = lrelu((v - mean) * inv * v_g[t] + v_be[t], 0.01f);
    float pv = v * v_w2[t];
#pragma unroll
    for (int m = 32; m >= 1; m >>= 1) pv += __shfl_xor(pv, m);
    __syncthreads();
    if ((t & 63) == 0) red[t >> 6] = pv;
    __syncthreads();
    if (t == 0) sc[0] = red[0] + red[1] + v_b2[0];
    // advantage branch
    float a = a_b1[t];
    for (int k = 0; k < 256; ++k) a += cf[k] * a_w1[k * 128 + t];
    ln_stats128(a, red, mean, inv);
    a = lrelu((a - mean) * inv * a_g[t] + a_be[t], 0.01f);
    hbuf[t] = a;
    __syncthreads();
    if (t < 10) {
        float s = a_b2[t];
        for (int c = 0; c < 128; ++c) s += hbuf[c] * a_w2[c * 10 + t];
        adv[t] = s;
    }
    __syncthreads();
    if (t == 0) {
        float m10 = 0.f;
        for (int o = 0; o < 10; ++o) m10 += adv[o];
        sc[1] = m10 * 0.1f;
    }
    __syncthreads();
    if (t < 10) out[t] = sc[0] + adv[t] - sc[1];
}

extern "C" void kernel_launch(void* const* d_in, const int* in_sizes, int n_in,
                              void* d_out, int out_size, void* d_ws, size_t ws_size,
                              hipStream_t stream)
{
    const float* x        = (const float*)d_in[0];
    const int*   ei       = (const int*)d_in[1];
    const float* ea       = (const float*)d_in[2];
    const float* tf       = (const float*)d_in[3];
    const float* emb_w    = (const float*)d_in[4];
    const float* emb_b    = (const float*)d_in[5];
    const float* emb_g    = (const float*)d_in[6];
    const float* emb_beta = (const float*)d_in[7];
    const float* gat_w    = (const float*)d_in[8];
    const float* gat_as   = (const float*)d_in[9];
    const float* gat_ad   = (const float*)d_in[10];
    const float* gat_bias = (const float*)d_in[11];
    const float* ec_w1    = (const float*)d_in[12];
    const float* ec_b1    = (const float*)d_in[13];
    const float* ec_g1    = (const float*)d_in[14];
    const float* ec_be1   = (const float*)d_in[15];
    const float* ec_w2    = (const float*)d_in[16];
    const float* ec_b2    = (const float*)d_in[17];
    const float* ec_g2    = (const float*)d_in[18];
    const float* ec_be2   = (const float*)d_in[19];
    const float* norm_g   = (const float*)d_in[20];
    const float* norm_b   = (const float*)d_in[21];
    const float* task_w   = (const float*)d_in[22];
    const float* task_b   = (const float*)d_in[23];
    const float* task_g   = (const float*)d_in[24];
    const float* task_be  = (const float*)d_in[25];
    const float* pa_w1    = (const float*)d_in[26];
    const float* pa_b1    = (const float*)d_in[27];
    const float* pa_w2    = (const float*)d_in[28];
    const float* pa_b2    = (const float*)d_in[29];
    const float* v_w1     = (const float*)d_in[30];
    const float* v_b1     = (const float*)d_in[31];
    const float* v_g      = (const float*)d_in[32];
    const float* v_be     = (const float*)d_in[33];
    const float* v_w2     = (const float*)d_in[34];
    const float* v_b2     = (const float*)d_in[35];
    const float* a_w1     = (const float*)d_in[36];
    const float* a_b1     = (const float*)d_in[37];
    const float* a_g      = (const float*)d_in[38];
    const float* a_be     = (const float*)d_in[39];
    const float* a_w2     = (const float*)d_in[40];
    const float* a_b2     = (const float*)d_in[41];

    const int n = in_sizes[0] / 128;   // 25000
    const int e = in_sizes[2];         // 400000
    const int* src = ei;
    const int* dst = ei + e;

    float* ws = (float*)d_ws;
    const size_t NR = (size_t)n * 128;
    float* h    = ws;
    float* x0   = ws + NR;
    float* ht   = ws + 2 * NR;
    float* A    = ws + 3 * NR;
    float* B    = ws + 4 * NR;
    float* xs   = ws + 5 * NR;
    float* a_s  = ws + 6 * NR;
    float* a_d  = a_s + (size_t)n * 2;
    float* den  = a_d + (size_t)n * 2;
    float* score = den + (size_t)n * 2;
    float* stats = score + n;
    float* gf    = stats + 2;

    const int ngb = (n + GROWS - 1) / GROWS;

    // embedding: h = lrelu(LN(x @ emb_w + emb_b)), x0 = h
    k_node_gemm<<<ngb, 256, 0, stream>>>(x, emb_w, emb_b, emb_g, emb_beta, h, x0, n, 1, 0.01f);

    for (int i = 0; i < LL; ++i) {
        k_node_gemm<<<ngb, 256, 0, stream>>>(h, gat_w + (size_t)i * 16384,
                                             nullptr, nullptr, nullptr, ht, nullptr, n, 0, 0.f);
        k_gat_scores<<<(n * 2 + 255) / 256, 256, 0, stream>>>(ht, gat_as + i * 128, gat_ad + i * 128,
                                                              a_s, a_d, n);
        k_node_gemm<<<ngb, 256, 0, stream>>>(h, ec_w1 + (size_t)i * 32768,
                                             nullptr, nullptr, nullptr, A, nullptr, n, 0, 0.f);
        k_node_gemm<<<ngb, 256, 0, stream>>>(h, ec_w1 + (size_t)i * 32768 + 16384,
                                             nullptr, nullptr, nullptr, B, nullptr, n, 0, 0.f);
        k_denom_init<<<(n * 2 + 255) / 256, 256, 0, stream>>>(a_s, a_d, den, n);
        k_edge_denom<<<(e * 2 + 255) / 256, 256, 0, stream>>>(src, dst, a_s, a_d, den, e);
        k_xsum_init<<<(n * 128 + 255) / 256, 256, 0, stream>>>(ht, a_s, a_d, den,
                                                               gat_bias + i * 128, xs, n);
        k_edge_main<<<(e + EB - 1) / EB, 512, 0, stream>>>(A, B, ht, src, dst, ea, a_s, a_d, den,
                                                           ec_w2 + (size_t)i * 16384,
                                                           ec_b1 + i * 128, ec_g1 + i * 128, ec_be1 + i * 128,
                                                           ec_b2 + i * 128, ec_g2 + i * 128, ec_be2 + i * 128,
                                                           xs, e);
        k_norm<<<n, 128, 0, stream>>>(xs, norm_g + i * 128, norm_b + i * 128, x0, h, n, i);
    }

    k_pool_score<<<(n + 3) / 4, 256, 0, stream>>>(h, pa_w1, pa_b1, pa_w2, pa_b2, score, n);
    k_softmax_reduce<<<1, 256, 0, stream>>>(score, stats, gf, n);
    k_gf<<<200, 128, 0, stream>>>(h, score, stats, gf, n);
    k_head<<<1, 128, 0, stream>>>(gf, tf, task_w, task_b, task_g, task_be,
                                  v_w1, v_b1, v_g, v_be, v_w2, v_b2,
                                  a_w1, a_b1, a_g, a_be, a_w2, a_b2,
                                  (float*)d_out);
}

// Round 2
// 1575.619 us; speedup vs baseline: 1.1067x; 1.1067x over previous
//
#include <hip/hip_runtime.h>
#include <math.h>

#define NN 25000
#define EE 400000
#define LL 3
#define LNEPS 1e-5f
#define GROWS 32
#define EB 64

typedef __attribute__((ext_vector_type(8))) short short8;
typedef __attribute__((ext_vector_type(16))) float f32x16;

__device__ __forceinline__ float lrelu(float x, float s) { return x >= 0.f ? x : s * x; }

__device__ __forceinline__ unsigned int pack_bf2(float lo, float hi) {
    unsigned int ul = __float_as_uint(lo), uh = __float_as_uint(hi);
    ul = (ul + 0x7FFFu + ((ul >> 16) & 1u)) >> 16;
    uh = (uh + 0x7FFFu + ((uh >> 16) & 1u)) >> 16;
    return (uh << 16) | (ul & 0xFFFFu);
}
__device__ __forceinline__ float bf_lo(unsigned int u) { return __uint_as_float(u << 16); }
__device__ __forceinline__ float bf_hi(unsigned int u) { return __uint_as_float(u & 0xFFFF0000u); }

// 128-thread block LN stats (2 waves)
__device__ __forceinline__ void ln_stats128(float v, float* red, float& mean, float& inv) {
    float sm = v, sq = v * v;
#pragma unroll
    for (int m = 32; m >= 1; m >>= 1) { sm += __shfl_xor(sm, m); sq += __shfl_xor(sq, m); }
    __syncthreads();
    if ((threadIdx.x & 63) == 0) { red[(threadIdx.x >> 6) * 2] = sm; red[(threadIdx.x >> 6) * 2 + 1] = sq; }
    __syncthreads();
    sm = red[0] + red[2]; sq = red[1] + red[3];
    mean = sm * (1.f / 128.f);
    float var = sq * (1.f / 128.f) - mean * mean;
    inv = rsqrtf(var + LNEPS);
}

// ---- node GEMM: out[n,128] = (opt LN+lrelu)(in[n,128] @ W[128,128] (+bias)) ----
__global__ __launch_bounds__(256) void k_node_gemm(
    const float* __restrict__ in, const float* __restrict__ W,
    const float* __restrict__ bias, const float* __restrict__ g,
    const float* __restrict__ be, float* __restrict__ out,
    float* __restrict__ out2, int nrows, int do_ln, float slope)
{
    __shared__ float sW[128 * 128];
    __shared__ float sIn[GROWS * 128];
    const int tid = threadIdx.x;
    {
        const float4* W4 = (const float4*)W;
        float4* sW4 = (float4*)sW;
#pragma unroll
        for (int i = 0; i < 16; ++i) sW4[tid + 256 * i] = W4[tid + 256 * i];
    }
    const int r0 = blockIdx.x * GROWS;
    {
        const float4* in4 = (const float4*)in;
        float4* sIn4 = (float4*)sIn;
#pragma unroll
        for (int i = 0; i < 4; ++i) {
            int idx = tid + 256 * i;
            int row = idx >> 5;
            sIn4[idx] = (r0 + row < nrows) ? in4[(size_t)r0 * 32 + idx]
                                           : make_float4(0.f, 0.f, 0.f, 0.f);
        }
    }
    __syncthreads();
    const int rt = tid >> 5, ct = tid & 31;
    float acc[4][4];
#pragma unroll
    for (int i = 0; i < 4; ++i) acc[i][0] = acc[i][1] = acc[i][2] = acc[i][3] = 0.f;
#pragma unroll 4
    for (int k = 0; k < 128; ++k) {
        float4 wv = *(const float4*)&sW[k * 128 + ct * 4];
#pragma unroll
        for (int i = 0; i < 4; ++i) {
            float a = sIn[(rt * 4 + i) * 128 + k];
            acc[i][0] += a * wv.x; acc[i][1] += a * wv.y;
            acc[i][2] += a * wv.z; acc[i][3] += a * wv.w;
        }
    }
    if (!do_ln) {
#pragma unroll
        for (int i = 0; i < 4; ++i) {
            int row = r0 + rt * 4 + i;
            if (row < nrows)
                *(float4*)&out[(size_t)row * 128 + ct * 4] =
                    make_float4(acc[i][0], acc[i][1], acc[i][2], acc[i][3]);
        }
    } else {
        float4 bv = *(const float4*)&bias[ct * 4];
        float4 gv = *(const float4*)&g[ct * 4];
        float4 ev = *(const float4*)&be[ct * 4];
        float rs[4], rq[4];
#pragma unroll
        for (int i = 0; i < 4; ++i) {
            acc[i][0] += bv.x; acc[i][1] += bv.y; acc[i][2] += bv.z; acc[i][3] += bv.w;
            rs[i] = acc[i][0] + acc[i][1] + acc[i][2] + acc[i][3];
            rq[i] = acc[i][0] * acc[i][0] + acc[i][1] * acc[i][1]
                  + acc[i][2] * acc[i][2] + acc[i][3] * acc[i][3];
        }
#pragma unroll
        for (int m = 16; m >= 1; m >>= 1) {
#pragma unroll
            for (int i = 0; i < 4; ++i) { rs[i] += __shfl_xor(rs[i], m); rq[i] += __shfl_xor(rq[i], m); }
        }
#pragma unroll
        for (int i = 0; i < 4; ++i) {
            int row = r0 + rt * 4 + i;
            float mean = rs[i] * (1.f / 128.f);
            float var = rq[i] * (1.f / 128.f) - mean * mean;
            float inv = rsqrtf(var + LNEPS);
            float4 o;
            o.x = lrelu((acc[i][0] - mean) * inv * gv.x + ev.x, slope);
            o.y = lrelu((acc[i][1] - mean) * inv * gv.y + ev.y, slope);
            o.z = lrelu((acc[i][2] - mean) * inv * gv.z + ev.z, slope);
            o.w = lrelu((acc[i][3] - mean) * inv * gv.w + ev.w, slope);
            if (row < nrows) {
                *(float4*)&out[(size_t)row * 128 + ct * 4] = o;
                if (out2) *(float4*)&out2[(size_t)row * 128 + ct * 4] = o;
            }
        }
    }
}

// ---- GAT attention scores a_s, a_d  [N,2] ----
__global__ void k_gat_scores(const float* __restrict__ ht, const float* __restrict__ as_,
                             const float* __restrict__ ad_, float* __restrict__ a_s,
                             float* __restrict__ a_d, int n)
{
    int idx = blockIdx.x * blockDim.x + threadIdx.x;
    if (idx >= n * 2) return;
    int node = idx >> 1, hd = idx & 1;
    const float4* row = (const float4*)(ht + (size_t)node * 128 + hd * 64);
    const float4* wsv = (const float4*)(as_ + hd * 64);
    const float4* wdv = (const float4*)(ad_ + hd * 64);
    float ss = 0.f, sd = 0.f;
#pragma unroll
    for (int i = 0; i < 16; ++i) {
        float4 v = row[i], vs = wsv[i], vd = wdv[i];
        ss += v.x * vs.x + v.y * vs.y + v.z * vs.z + v.w * vs.w;
        sd += v.x * vd.x + v.y * vd.y + v.z * vd.z + v.w * vd.w;
    }
    a_s[idx] = ss; a_d[idx] = sd;
}

// ---- denom init with self-loop term ----
__global__ void k_denom_init(const float* __restrict__ a_s, const float* __restrict__ a_d,
                             float* __restrict__ denom, int n)
{
    int idx = blockIdx.x * blockDim.x + threadIdx.x;
    if (idx >= n * 2) return;
    float e = lrelu(a_s[idx] + a_d[idx], 0.2f);
    denom[idx] = expf(e);
}

// ---- accumulate exp(e) per dst over edges ----
__global__ void k_edge_denom(const int* __restrict__ src, const int* __restrict__ dst,
                             const float* __restrict__ a_s, const float* __restrict__ a_d,
                             float* __restrict__ denom, int ne)
{
    int idx = blockIdx.x * blockDim.x + threadIdx.x;
    if (idx >= ne * 2) return;
    int e = idx >> 1, hd = idx & 1;
    int s = src[e], d = dst[e];
    float ev = lrelu(a_s[s * 2 + hd] + a_d[d * 2 + hd], 0.2f);
    atomicAdd(&denom[d * 2 + hd], expf(ev));
}

// ---- xsum = gat_bias + self-loop GAT contribution ----
__global__ void k_xsum_init(const float* __restrict__ ht, const float* __restrict__ a_s,
                            const float* __restrict__ a_d, const float* __restrict__ denom,
                            const float* __restrict__ gbias, float* __restrict__ xsum, int n)
{
    int idx = blockIdx.x * blockDim.x + threadIdx.x;
    if (idx >= n * 128) return;
    int node = idx >> 7, c = idx & 127, hd = c >> 6;
    float es = lrelu(a_s[node * 2 + hd] + a_d[node * 2 + hd], 0.2f);
    float alpha = expf(es) / denom[node * 2 + hd];
    xsum[idx] = gbias[c] + ht[idx] * alpha;
}

// ---- fused edge kernel: EdgeConv MLP (factored A+B, MFMA phase-2) + GAT scatter ----
__global__ __launch_bounds__(512) void k_edge_main(
    const float* __restrict__ Abuf, const float* __restrict__ Bbuf,
    const float* __restrict__ ht,
    const int* __restrict__ src, const int* __restrict__ dst,
    const float* __restrict__ ea,
    const float* __restrict__ a_s, const float* __restrict__ a_d,
    const float* __restrict__ denom,
    const float* __restrict__ W2,
    const float* __restrict__ b1, const float* __restrict__ g1, const float* __restrict__ be1,
    const float* __restrict__ b2, const float* __restrict__ g2, const float* __restrict__ be2,
    float* __restrict__ xsum, int ne)
{
    // sWB: W2 staged in B-fragment order (bf16, 32KB). After phase 2 it is
    // reused (union) as the fp32 u-tile sU[64][128] (32KB).
    __shared__ __align__(16) unsigned int sWB[2048 * 4];
    __shared__ __align__(16) unsigned int sT32[EB * 64];   // t tile as bf16 pairs, 16KB
    __shared__ int   sS[EB], sD[EB];
    __shared__ float sEA[EB];
    __shared__ float sAl[EB * 2];
    __shared__ float sB1[128], sG1[128], sE1[128], sB2[128], sG2[128], sE2[128];
    float* sU = (float*)sWB;

    const int tid = threadIdx.x;
    {   // stage W2 -> bf16 B-fragment layout:
        // flat f = (nb*8 + ks)*64 + lane ; uint4 = W2[k0..k0+7][nb*32 + (lane&31)]
        // with k0 = ks*16 + (lane>>5)*8  (layout of v_mfma_f32_32x32x16_bf16 B operand)
        uint4* sWB4 = (uint4*)sWB;
#pragma unroll
        for (int i = 0; i < 4; ++i) {
            int f = tid + 512 * i;
            int l = f & 63;
            int k0 = ((f >> 6) & 7) * 16 + (l >> 5) * 8;
            int col = (f >> 9) * 32 + (l & 31);
            const float* wp = W2 + (size_t)k0 * 128 + col;
            uint4 r;
            r.x = pack_bf2(wp[0],   wp[128]);
            r.y = pack_bf2(wp[256], wp[384]);
            r.z = pack_bf2(wp[512], wp[640]);
            r.w = pack_bf2(wp[768], wp[896]);
            sWB4[f] = r;
        }
    }
    if (tid < 128) {
        sB1[tid] = b1[tid]; sG1[tid] = g1[tid]; sE1[tid] = be1[tid];
        sB2[tid] = b2[tid]; sG2[tid] = g2[tid]; sE2[tid] = be2[tid];
    }
    const int e0 = blockIdx.x * EB;
    const int nev = (ne - e0 < EB) ? (ne - e0) : EB;
    if (tid < EB) {
        if (tid < nev) { sS[tid] = src[e0 + tid]; sD[tid] = dst[e0 + tid]; sEA[tid] = ea[e0 + tid]; }
        else           { sS[tid] = 0; sD[tid] = 0; sEA[tid] = 0.f; }
    }
    if (tid < 2 * EB) {
        int le = tid >> 1, hd = tid & 1;
        float al = 0.f;
        if (le < nev) {
            int e = e0 + le;
            int s = src[e], d = dst[e];
            float ev = lrelu(a_s[s * 2 + hd] + a_d[d * 2 + hd], 0.2f);
            al = expf(ev) / denom[d * 2 + hd];
        }
        sAl[le * 2 + hd] = al;
    }
    __syncthreads();

    // phase 1: t = lrelu(LN(A[src]+B[dst]+b1), 0.2) -> bf16 LDS
    const int wv = tid >> 6, ln = tid & 63;
    for (int j = 0; j < 8; ++j) {
        int e = wv * 8 + j;
        if (e < nev) {
            int s = sS[e], d = sD[e];
            float2 av = *(const float2*)&Abuf[(size_t)s * 128 + ln * 2];
            float2 bv = *(const float2*)&Bbuf[(size_t)d * 128 + ln * 2];
            float v0 = av.x + bv.x + sB1[ln * 2];
            float v1 = av.y + bv.y + sB1[ln * 2 + 1];
            float sm = v0 + v1, sq = v0 * v0 + v1 * v1;
#pragma unroll
            for (int m = 32; m >= 1; m >>= 1) { sm += __shfl_xor(sm, m); sq += __shfl_xor(sq, m); }
            float mean = sm * (1.f / 128.f);
            float var = sq * (1.f / 128.f) - mean * mean;
            float inv = rsqrtf(var + LNEPS);
            v0 = lrelu((v0 - mean) * inv * sG1[ln * 2] + sE1[ln * 2], 0.2f);
            v1 = lrelu((v1 - mean) * inv * sG1[ln * 2 + 1] + sE1[ln * 2 + 1], 0.2f);
            sT32[e * 64 + ln] = pack_bf2(v0, v1);
        }
    }
    __syncthreads();

    // phase 2: u = t @ W2 via MFMA. 8 waves, each one 32x32 output tile.
    // A-frag (t): lane l holds row m0+(l&31), k = ks*16 + (l>>5)*8 + {0..7}
    // B-frag (W2): staged in sWB at flat uint4 index ((w&3)*8 + ks)*64 + l
    {
        const int w = wv, l = ln;
        const int m0 = (w >> 2) * 32, n0 = (w & 3) * 32;
        f32x16 acc = {};
#pragma unroll
        for (int ks = 0; ks < 8; ++ks) {
            short8 a = *(const short8*)&sT32[(m0 + (l & 31)) * 64 + ks * 8 + (l >> 5) * 4];
            short8 b = *(const short8*)&sWB[((((w & 3) * 8 + ks) * 64 + l)) * 4];
            acc = __builtin_amdgcn_mfma_f32_32x32x16_bf16(a, b, acc, 0, 0, 0);
        }
        __syncthreads();   // all waves done reading sWB before overwriting as sU
        float b2c = sB2[n0 + (l & 31)];
#pragma unroll
        for (int r = 0; r < 16; ++r) {
            int row = m0 + (r & 3) + 8 * (r >> 2) + 4 * (l >> 5);
            sU[row * 128 + n0 + (l & 31)] = acc[r] + b2c;
        }
    }
    __syncthreads();

    // phase 3: LN(u)+lrelu, *edge_attr, + GAT ht[src]*alpha, atomic scatter to xsum[dst]
    for (int j = 0; j < 8; ++j) {
        int e = wv * 8 + j;
        if (e < nev) {
            int s = sS[e], d = sD[e];
            float2 uv = *(const float2*)&sU[e * 128 + ln * 2];
            float u0 = uv.x, u1 = uv.y;
            float sm = u0 + u1, sq = u0 * u0 + u1 * u1;
#pragma unroll
            for (int m = 32; m >= 1; m >>= 1) { sm += __shfl_xor(sm, m); sq += __shfl_xor(sq, m); }
            float mean = sm * (1.f / 128.f);
            float var = sq * (1.f / 128.f) - mean * mean;
            float inv = rsqrtf(var + LNEPS);
            float eav = sEA[e];
            float v0 = lrelu((u0 - mean) * inv * sG2[ln * 2] + sE2[ln * 2], 0.2f) * eav;
            float v1 = lrelu((u1 - mean) * inv * sG2[ln * 2 + 1] + sE2[ln * 2 + 1], 0.2f) * eav;
            float al = sAl[e * 2 + (ln >> 5)];
            float2 hv = *(const float2*)&ht[(size_t)s * 128 + ln * 2];
            v0 += hv.x * al;
            v1 += hv.y * al;
            atomicAdd(&xsum[(size_t)d * 128 + ln * 2], v0);
            atomicAdd(&xsum[(size_t)d * 128 + ln * 2 + 1], v1);
        }
    }
}

// ---- h = lrelu(LN(xsum)) (+ x0 residual, update x0) ----
__global__ __launch_bounds__(128) void k_norm(const float* __restrict__ xsum,
                                              const float* __restrict__ g,
                                              const float* __restrict__ b,
                                              float* __restrict__ x0,
                                              float* __restrict__ h, int n, int layer)
{
    __shared__ float red[4];
    int node = blockIdx.x, c = threadIdx.x;
    float v = xsum[(size_t)node * 128 + c];
    float mean, inv;
    ln_stats128(v, red, mean, inv);
    float val = lrelu((v - mean) * inv * g[c] + b[c], 0.01f);
    if (layer > 0) {
        val += x0[(size_t)node * 128 + c];
        x0[(size_t)node * 128 + c] = val;
    }
    h[(size_t)node * 128 + c] = val;
}

// ---- pooling attention scores (one node per wave) ----
__global__ __launch_bounds__(256) void k_pool_score(const float* __restrict__ h,
    const float* __restrict__ w1, const float* __restrict__ b1,
    const float* __restrict__ w2, const float* __restrict__ b2,
    float* __restrict__ score, int n)
{
    int wv = threadIdx.x >> 6, ln = threadIdx.x & 63;
    int node = blockIdx.x * 4 + wv;
    if (node >= n) return;
    float acc = b1[ln];
    const float* hr = h + (size_t)node * 128;
    for (int k = 0; k < 128; ++k) acc += hr[k] * w1[k * 64 + ln];
    acc = lrelu(acc, 0.01f) * w2[ln];
#pragma unroll
    for (int m = 32; m >= 1; m >>= 1) acc += __shfl_xor(acc, m);
    if (ln == 0) score[node] = acc + b2[0];
}

// ---- softmax stats (single block) + zero gf ----
__global__ __launch_bounds__(256) void k_softmax_reduce(const float* __restrict__ score,
                                                        float* __restrict__ stats,
                                                        float* __restrict__ gf, int n)
{
    __shared__ float red[8];
    int t = threadIdx.x;
    float mx = -1e30f;
    for (int i = t; i < n; i += 256) mx = fmaxf(mx, score[i]);
#pragma unroll
    for (int m = 32; m >= 1; m >>= 1) mx = fmaxf(mx, __shfl_xor(mx, m));
    if ((t & 63) == 0) red[t >> 6] = mx;
    __syncthreads();
    mx = fmaxf(fmaxf(red[0], red[1]), fmaxf(red[2], red[3]));
    float s = 0.f;
    for (int i = t; i < n; i += 256) s += expf(score[i] - mx);
#pragma unroll
    for (int m = 32; m >= 1; m >>= 1) s += __shfl_xor(s, m);
    if ((t & 63) == 0) red[4 + (t >> 6)] = s;
    __syncthreads();
    s = red[4] + red[5] + red[6] + red[7];
    if (t == 0) { stats[0] = mx; stats[1] = s; }
    if (t < 128) gf[t] = 0.f;
}

// ---- gf = sum_n softmax(score)[n] * h[n,:] ----
__global__ __launch_bounds__(128) void k_gf(const float* __restrict__ h,
                                            const float* __restrict__ score,
                                            const float* __restrict__ stats,
                                            float* __restrict__ gf, int n)
{
    int c = threadIdx.x;
    float mx = stats[0], invZ = 1.f / stats[1];
    int per = (n + gridDim.x - 1) / gridDim.x;
    int n0 = blockIdx.x * per;
    int n1 = n0 + per; if (n1 > n) n1 = n;
    float acc = 0.f;
    for (int i = n0; i < n1; ++i)
        acc += expf(score[i] - mx) * invZ * h[(size_t)i * 128 + c];
    atomicAdd(&gf[c], acc);
}

// ---- final head (single 128-thread block) ----
__global__ __launch_bounds__(128) void k_head(
    const float* __restrict__ gf, const float* __restrict__ tf,
    const float* __restrict__ task_w, const float* __restrict__ task_b,
    const float* __restrict__ task_g, const float* __restrict__ task_be,
    const float* __restrict__ v_w1, const float* __restrict__ v_b1,
    const float* __restrict__ v_g, const float* __restrict__ v_be,
    const float* __restrict__ v_w2, const float* __restrict__ v_b2,
    const float* __restrict__ a_w1, const float* __restrict__ a_b1,
    const float* __restrict__ a_g, const float* __restrict__ a_be,
    const float* __restrict__ a_w2, const float* __restrict__ a_b2,
    float* __restrict__ out)
{
    __shared__ float cf[256], hbuf[128], red[4], sc[2], adv[10];
    int t = threadIdx.x;
    float mean, inv;
    // task embedding
    float te = task_b[t];
#pragma unroll
    for (int k = 0; k < 4; ++k) te += tf[k] * task_w[k * 128 + t];
    ln_stats128(te, red, mean, inv);
    te = lrelu((te - mean) * inv * task_g[t] + task_be[t], 0.01f);
    cf[t] = gf[t]; cf[128 + t] = te;
    __syncthreads();
    // value branch
    float v = v_b1[t];
    for (int k = 0; k < 256; ++k) v += cf[k] * v_w1[k * 128 + t];
    ln_stats128(v, red, mean, inv);
    v = lrelu((v - mean) * inv * v_g[t] + v_be[t], 0.01f);
    float pv = v * v_w2[t];
#pragma unroll
    for (int m = 32; m >= 1; m >>= 1) pv += __shfl_xor(pv, m);
    __syncthreads();
    if ((t & 63) == 0) red[t >> 6] = pv;
    __syncthreads();
    if (t == 0) sc[0] = red[0] + red[1] + v_b2[0];
    // advantage branch
    float a = a_b1[t];
    for (int k = 0; k < 256; ++k) a += cf[k] * a_w1[k * 128 + t];
    ln_stats128(a, red, mean, inv);
    a = lrelu((a - mean) * inv * a_g[t] + a_be[t], 0.01f);
    hbuf[t] = a;
    __syncthreads();
    if (t < 10) {
        float s = a_b2[t];
        for (int c = 0; c < 128; ++c) s += hbuf[c] * a_w2[c * 10 + t];
        adv[t] = s;
    }
    __syncthreads();
    if (t == 0) {
        float m10 = 0.f;
        for (int o = 0; o < 10; ++o) m10 += adv[o];
        sc[1] = m10 * 0.1f;
    }
    __syncthreads();
    if (t < 10) out[t] = sc[0] + adv[t] - sc[1];
}

extern "C" void kernel_launch(void* const* d_in, const int* in_sizes, int n_in,
                              void* d_out, int out_size, void* d_ws, size_t ws_size,
                              hipStream_t stream)
{
    const float* x        = (const float*)d_in[0];
    const int*   ei       = (const int*)d_in[1];
    const float* ea       = (const float*)d_in[2];
    const float* tf       = (const float*)d_in[3];
    const float* emb_w    = (const float*)d_in[4];
    const float* emb_b    = (const float*)d_in[5];
    const float* emb_g    = (const float*)d_in[6];
    const float* emb_beta = (const float*)d_in[7];
    const float* gat_w    = (const float*)d_in[8];
    const float* gat_as   = (const float*)d_in[9];
    const float* gat_ad   = (const float*)d_in[10];
    const float* gat_bias = (const float*)d_in[11];
    const float* ec_w1    = (const float*)d_in[12];
    const float* ec_b1    = (const float*)d_in[13];
    const float* ec_g1    = (const float*)d_in[14];
    const float* ec_be1   = (const float*)d_in[15];
    const float* ec_w2    = (const float*)d_in[16];
    const float* ec_b2    = (const float*)d_in[17];
    const float* ec_g2    = (const float*)d_in[18];
    const float* ec_be2   = (const float*)d_in[19];
    const float* norm_g   = (const float*)d_in[20];
    const float* norm_b   = (const float*)d_in[21];
    const float* task_w   = (const float*)d_in[22];
    const float* task_b   = (const float*)d_in[23];
    const float* task_g   = (const float*)d_in[24];
    const float* task_be  = (const float*)d_in[25];
    const float* pa_w1    = (const float*)d_in[26];
    const float* pa_b1    = (const float*)d_in[27];
    const float* pa_w2    = (const float*)d_in[28];
    const float* pa_b2    = (const float*)d_in[29];
    const float* v_w1     = (const float*)d_in[30];
    const float* v_b1     = (const float*)d_in[31];
    const float* v_g      = (const float*)d_in[32];
    const float* v_be     = (const float*)d_in[33];
    const float* v_w2     = (const float*)d_in[34];
    const float* v_b2     = (const float*)d_in[35];
    const float* a_w1     = (const float*)d_in[36];
    const float* a_b1     = (const float*)d_in[37];
    const float* a_g      = (const float*)d_in[38];
    const float* a_be     = (const float*)d_in[39];
    const float* a_w2     = (const float*)d_in[40];
    const float* a_b2     = (const float*)d_in[41];

    const int n = in_sizes[0] / 128;   // 25000
    const int e = in_sizes[2];         // 400000
    const int* src = ei;
    const int* dst = ei + e;

    float* ws = (float*)d_ws;
    const size_t NR = (size_t)n * 128;
    float* h    = ws;
    float* x0   = ws + NR;
    float* ht   = ws + 2 * NR;
    float* A    = ws + 3 * NR;
    float* B    = ws + 4 * NR;
    float* xs   = ws + 5 * NR;
    float* a_s  = ws + 6 * NR;
    float* a_d  = a_s + (size_t)n * 2;
    float* den  = a_d + (size_t)n * 2;
    float* score = den + (size_t)n * 2;
    float* stats = score + n;
    float* gf    = stats + 2;

    const int ngb = (n + GROWS - 1) / GROWS;

    // embedding: h = lrelu(LN(x @ emb_w + emb_b)), x0 = h
    k_node_gemm<<<ngb, 256, 0, stream>>>(x, emb_w, emb_b, emb_g, emb_beta, h, x0, n, 1, 0.01f);

    for (int i = 0; i < LL; ++i) {
        k_node_gemm<<<ngb, 256, 0, stream>>>(h, gat_w + (size_t)i * 16384,
                                             nullptr, nullptr, nullptr, ht, nullptr, n, 0, 0.f);
        k_gat_scores<<<(n * 2 + 255) / 256, 256, 0, stream>>>(ht, gat_as + i * 128, gat_ad + i * 128,
                                                              a_s, a_d, n);
        k_node_gemm<<<ngb, 256, 0, stream>>>(h, ec_w1 + (size_t)i * 32768,
                                             nullptr, nullptr, nullptr, A, nullptr, n, 0, 0.f);
        k_node_gemm<<<ngb, 256, 0, stream>>>(h, ec_w1 + (size_t)i * 32768 + 16384,
                                             nullptr, nullptr, nullptr, B, nullptr, n, 0, 0.f);
        k_denom_init<<<(n * 2 + 255) / 256, 256, 0, stream>>>(a_s, a_d, den, n);
        k_edge_denom<<<(e * 2 + 255) / 256, 256, 0, stream>>>(src, dst, a_s, a_d, den, e);
        k_xsum_init<<<(n * 128 + 255) / 256, 256, 0, stream>>>(ht, a_s, a_d, den,
                                                               gat_bias + i * 128, xs, n);
        k_edge_main<<<(e + EB - 1) / EB, 512, 0, stream>>>(A, B, ht, src, dst, ea, a_s, a_d, den,
                                                           ec_w2 + (size_t)i * 16384,
                                                           ec_b1 + i * 128, ec_g1 + i * 128, ec_be1 + i * 128,
                                                           ec_b2 + i * 128, ec_g2 + i * 128, ec_be2 + i * 128,
                                                           xs, e);
        k_norm<<<n, 128, 0, stream>>>(xs, norm_g + i * 128, norm_b + i * 128, x0, h, n, i);
    }

    k_pool_score<<<(n + 3) / 4, 256, 0, stream>>>(h, pa_w1, pa_b1, pa_w2, pa_b2, score, n);
    k_softmax_reduce<<<1, 256, 0, stream>>>(score, stats, gf, n);
    k_gf<<<200, 128, 0, stream>>>(h, score, stats, gf, n);
    k_head<<<1, 128, 0, stream>>>(gf, tf, task_w, task_b, task_g, task_be,
                                  v_w1, v_b1, v_g, v_be, v_w2, v_b2,
                                  a_w1, a_b1, a_g, a_be, a_w2, a_b2,
                                  (float*)d_out);
}

// Round 3
// 1021.929 us; speedup vs baseline: 1.7063x; 1.5418x over previous
//
#include <hip/hip_runtime.h>
#include <math.h>

#define NN 25000
#define EE 400000
#define LL 3
#define LNEPS 1e-5f
#define GROWS 32
#define EB 64

typedef __attribute__((ext_vector_type(8))) short short8;
typedef __attribute__((ext_vector_type(16))) float f32x16;

__device__ __forceinline__ float lrelu(float x, float s) { return x >= 0.f ? x : s * x; }

__device__ __forceinline__ unsigned int pack_bf2(float lo, float hi) {
    unsigned int ul = __float_as_uint(lo), uh = __float_as_uint(hi);
    ul = (ul + 0x7FFFu + ((ul >> 16) & 1u)) >> 16;
    uh = (uh + 0x7FFFu + ((uh >> 16) & 1u)) >> 16;
    return (uh << 16) | (ul & 0xFFFFu);
}

// 128-thread block LN stats (2 waves)
__device__ __forceinline__ void ln_stats128(float v, float* red, float& mean, float& inv) {
    float sm = v, sq = v * v;
#pragma unroll
    for (int m = 32; m >= 1; m >>= 1) { sm += __shfl_xor(sm, m); sq += __shfl_xor(sq, m); }
    __syncthreads();
    if ((threadIdx.x & 63) == 0) { red[(threadIdx.x >> 6) * 2] = sm; red[(threadIdx.x >> 6) * 2 + 1] = sq; }
    __syncthreads();
    sm = red[0] + red[2]; sq = red[1] + red[3];
    mean = sm * (1.f / 128.f);
    float var = sq * (1.f / 128.f) - mean * mean;
    inv = rsqrtf(var + LNEPS);
}

// ================= edge sorting (counting sort by dst) =================
__global__ void k_hist(const int* __restrict__ dst, int* __restrict__ cnt, int ne)
{
    int i = blockIdx.x * 256 + threadIdx.x;
    if (i < ne) atomicAdd(&cnt[dst[i]], 1);
}

__global__ __launch_bounds__(1024) void k_scan(const int* __restrict__ cnt,
                                               int* __restrict__ starts, int n)
{
    __shared__ int tot[1024];
    int t = threadIdx.x;
    const int PER = (n + 1023) >> 10;
    int i0 = t * PER;
    int s = 0;
    for (int k = 0; k < PER; ++k) { int i = i0 + k; s += (i < n) ? cnt[i] : 0; }
    tot[t] = s;
    __syncthreads();
    for (int off = 1; off < 1024; off <<= 1) {
        int x = (t >= off) ? tot[t - off] : 0;
        __syncthreads();
        tot[t] += x;
        __syncthreads();
    }
    int run = (t > 0) ? tot[t - 1] : 0;
    for (int k = 0; k < PER; ++k) {
        int i = i0 + k;
        if (i < n) { starts[i] = run; run += cnt[i]; }
    }
    if (t == 1023) starts[n] = tot[1023];
}

__global__ void k_scatter(const int* __restrict__ src, const int* __restrict__ dst,
                          const float* __restrict__ ea, int* __restrict__ cursor,
                          int* __restrict__ s_src, int* __restrict__ s_dst,
                          float* __restrict__ s_ea, int ne)
{
    int i = blockIdx.x * 256 + threadIdx.x;
    if (i >= ne) return;
    int d = dst[i];
    int pos = atomicAdd(&cursor[d], 1);
    s_src[pos] = src[i];
    s_dst[pos] = d;
    s_ea[pos] = ea[i];
}

// ---- node GEMM: out[n,128] = (opt LN+lrelu)(in[n,128] @ W[128,128] (+bias)) ----
__global__ __launch_bounds__(256) void k_node_gemm(
    const float* __restrict__ in, const float* __restrict__ W,
    const float* __restrict__ bias, const float* __restrict__ g,
    const float* __restrict__ be, float* __restrict__ out,
    float* __restrict__ out2, int nrows, int do_ln, float slope)
{
    __shared__ float sW[128 * 128];
    __shared__ float sIn[GROWS * 128];
    const int tid = threadIdx.x;
    {
        const float4* W4 = (const float4*)W;
        float4* sW4 = (float4*)sW;
#pragma unroll
        for (int i = 0; i < 16; ++i) sW4[tid + 256 * i] = W4[tid + 256 * i];
    }
    const int r0 = blockIdx.x * GROWS;
    {
        const float4* in4 = (const float4*)in;
        float4* sIn4 = (float4*)sIn;
#pragma unroll
        for (int i = 0; i < 4; ++i) {
            int idx = tid + 256 * i;
            int row = idx >> 5;
            sIn4[idx] = (r0 + row < nrows) ? in4[(size_t)r0 * 32 + idx]
                                           : make_float4(0.f, 0.f, 0.f, 0.f);
        }
    }
    __syncthreads();
    const int rt = tid >> 5, ct = tid & 31;
    float acc[4][4];
#pragma unroll
    for (int i = 0; i < 4; ++i) acc[i][0] = acc[i][1] = acc[i][2] = acc[i][3] = 0.f;
#pragma unroll 4
    for (int k = 0; k < 128; ++k) {
        float4 wv = *(const float4*)&sW[k * 128 + ct * 4];
#pragma unroll
        for (int i = 0; i < 4; ++i) {
            float a = sIn[(rt * 4 + i) * 128 + k];
            acc[i][0] += a * wv.x; acc[i][1] += a * wv.y;
            acc[i][2] += a * wv.z; acc[i][3] += a * wv.w;
        }
    }
    if (!do_ln) {
#pragma unroll
        for (int i = 0; i < 4; ++i) {
            int row = r0 + rt * 4 + i;
            if (row < nrows)
                *(float4*)&out[(size_t)row * 128 + ct * 4] =
                    make_float4(acc[i][0], acc[i][1], acc[i][2], acc[i][3]);
        }
    } else {
        float4 bv = *(const float4*)&bias[ct * 4];
        float4 gv = *(const float4*)&g[ct * 4];
        float4 ev = *(const float4*)&be[ct * 4];
        float rs[4], rq[4];
#pragma unroll
        for (int i = 0; i < 4; ++i) {
            acc[i][0] += bv.x; acc[i][1] += bv.y; acc[i][2] += bv.z; acc[i][3] += bv.w;
            rs[i] = acc[i][0] + acc[i][1] + acc[i][2] + acc[i][3];
            rq[i] = acc[i][0] * acc[i][0] + acc[i][1] * acc[i][1]
                  + acc[i][2] * acc[i][2] + acc[i][3] * acc[i][3];
        }
#pragma unroll
        for (int m = 16; m >= 1; m >>= 1) {
#pragma unroll
            for (int i = 0; i < 4; ++i) { rs[i] += __shfl_xor(rs[i], m); rq[i] += __shfl_xor(rq[i], m); }
        }
#pragma unroll
        for (int i = 0; i < 4; ++i) {
            int row = r0 + rt * 4 + i;
            float mean = rs[i] * (1.f / 128.f);
            float var = rq[i] * (1.f / 128.f) - mean * mean;
            float inv = rsqrtf(var + LNEPS);
            float4 o;
            o.x = lrelu((acc[i][0] - mean) * inv * gv.x + ev.x, slope);
            o.y = lrelu((acc[i][1] - mean) * inv * gv.y + ev.y, slope);
            o.z = lrelu((acc[i][2] - mean) * inv * gv.z + ev.z, slope);
            o.w = lrelu((acc[i][3] - mean) * inv * gv.w + ev.w, slope);
            if (row < nrows) {
                *(float4*)&out[(size_t)row * 128 + ct * 4] = o;
                if (out2) *(float4*)&out2[(size_t)row * 128 + ct * 4] = o;
            }
        }
    }
}

// ---- GAT attention scores a_s, a_d  [N,2] ----
__global__ void k_gat_scores(const float* __restrict__ ht, const float* __restrict__ as_,
                             const float* __restrict__ ad_, float* __restrict__ a_s,
                             float* __restrict__ a_d, int n)
{
    int idx = blockIdx.x * blockDim.x + threadIdx.x;
    if (idx >= n * 2) return;
    int node = idx >> 1, hd = idx & 1;
    const float4* row = (const float4*)(ht + (size_t)node * 128 + hd * 64);
    const float4* wsv = (const float4*)(as_ + hd * 64);
    const float4* wdv = (const float4*)(ad_ + hd * 64);
    float ss = 0.f, sd = 0.f;
#pragma unroll
    for (int i = 0; i < 16; ++i) {
        float4 v = row[i], vs = wsv[i], vd = wdv[i];
        ss += v.x * vs.x + v.y * vs.y + v.z * vs.z + v.w * vs.w;
        sd += v.x * vd.x + v.y * vd.y + v.z * vd.z + v.w * vd.w;
    }
    a_s[idx] = ss; a_d[idx] = sd;
}

// ---- denom init with self-loop term ----
__global__ void k_denom_init(const float* __restrict__ a_s, const float* __restrict__ a_d,
                             float* __restrict__ denom, int n)
{
    int idx = blockIdx.x * blockDim.x + threadIdx.x;
    if (idx >= n * 2) return;
    float e = lrelu(a_s[idx] + a_d[idx], 0.2f);
    denom[idx] = expf(e);
}

// ---- accumulate exp(e) per dst over sorted edges, run-merged ----
__global__ void k_edge_denom2(const int* __restrict__ s_src, const int* __restrict__ s_dst,
                              const float* __restrict__ a_s, const float* __restrict__ a_d,
                              float* __restrict__ denom, int ne)
{
    int base = (blockIdx.x * 256 + threadIdx.x) * 8;
    if (base >= ne) return;
    int curd = -1;
    float acc0 = 0.f, acc1 = 0.f;
    for (int k = 0; k < 8; ++k) {
        int e = base + k;
        if (e >= ne) break;
        int s = s_src[e], d = s_dst[e];
        float v0 = expf(lrelu(a_s[s * 2]     + a_d[d * 2],     0.2f));
        float v1 = expf(lrelu(a_s[s * 2 + 1] + a_d[d * 2 + 1], 0.2f));
        if (d != curd) {
            if (curd >= 0) { atomicAdd(&denom[curd * 2], acc0); atomicAdd(&denom[curd * 2 + 1], acc1); }
            curd = d; acc0 = v0; acc1 = v1;
        } else { acc0 += v0; acc1 += v1; }
    }
    if (curd >= 0) { atomicAdd(&denom[curd * 2], acc0); atomicAdd(&denom[curd * 2 + 1], acc1); }
}

// ---- xsum = gat_bias + self-loop GAT contribution ----
__global__ void k_xsum_init(const float* __restrict__ ht, const float* __restrict__ a_s,
                            const float* __restrict__ a_d, const float* __restrict__ denom,
                            const float* __restrict__ gbias, float* __restrict__ xsum, int n)
{
    int idx = blockIdx.x * blockDim.x + threadIdx.x;
    if (idx >= n * 128) return;
    int node = idx >> 7, c = idx & 127, hd = c >> 6;
    float es = lrelu(a_s[node * 2 + hd] + a_d[node * 2 + hd], 0.2f);
    float alpha = expf(es) / denom[node * 2 + hd];
    xsum[idx] = gbias[c] + ht[idx] * alpha;
}

// ---- fused edge kernel (dst-sorted): EdgeConv MLP (MFMA) + GAT, run-merged scatter ----
__global__ __launch_bounds__(512) void k_edge_main(
    const float* __restrict__ Abuf, const float* __restrict__ Bbuf,
    const float* __restrict__ ht,
    const int* __restrict__ s_src, const int* __restrict__ s_dst,
    const float* __restrict__ s_ea,
    const float* __restrict__ a_s, const float* __restrict__ a_d,
    const float* __restrict__ denom,
    const float* __restrict__ W2,
    const float* __restrict__ b1, const float* __restrict__ g1, const float* __restrict__ be1,
    const float* __restrict__ b2, const float* __restrict__ g2, const float* __restrict__ be2,
    float* __restrict__ xsum, int ne)
{
    // sWB: W2 staged in B-fragment order (bf16, 32KB); reused after phase 2 as fp32 sU[64][128].
    __shared__ __align__(16) unsigned int sWB[2048 * 4];
    __shared__ __align__(16) unsigned int sT32[EB * 64];   // t tile bf16 pairs, XOR-swizzled
    __shared__ int   sS[EB], sD[EB];
    __shared__ float sEA[EB];
    __shared__ float sAl[EB * 2];
    __shared__ float sB1[128], sG1[128], sE1[128], sB2[128], sG2[128], sE2[128];
    float* sU = (float*)sWB;

    const int tid = threadIdx.x;
    {   // stage W2 -> bf16 B-fragment layout for v_mfma_f32_32x32x16_bf16
        uint4* sWB4 = (uint4*)sWB;
#pragma unroll
        for (int i = 0; i < 4; ++i) {
            int f = tid + 512 * i;
            int l = f & 63;
            int k0 = ((f >> 6) & 7) * 16 + (l >> 5) * 8;
            int col = (f >> 9) * 32 + (l & 31);
            const float* wp = W2 + (size_t)k0 * 128 + col;
            uint4 r;
            r.x = pack_bf2(wp[0],   wp[128]);
            r.y = pack_bf2(wp[256], wp[384]);
            r.z = pack_bf2(wp[512], wp[640]);
            r.w = pack_bf2(wp[768], wp[896]);
            sWB4[f] = r;
        }
    }
    if (tid < 128) {
        sB1[tid] = b1[tid]; sG1[tid] = g1[tid]; sE1[tid] = be1[tid];
        sB2[tid] = b2[tid]; sG2[tid] = g2[tid]; sE2[tid] = be2[tid];
    }
    const int e0 = blockIdx.x * EB;
    const int nev = (ne - e0 < EB) ? (ne - e0) : EB;
    if (tid < EB) {
        if (tid < nev) { sS[tid] = s_src[e0 + tid]; sD[tid] = s_dst[e0 + tid]; sEA[tid] = s_ea[e0 + tid]; }
        else           { sS[tid] = 0; sD[tid] = -1; sEA[tid] = 0.f; }
    }
    if (tid < 2 * EB) {
        int le = tid >> 1, hd = tid & 1;
        float al = 0.f;
        if (le < nev) {
            int e = e0 + le;
            int s = s_src[e], d = s_dst[e];
            float ev = lrelu(a_s[s * 2 + hd] + a_d[d * 2 + hd], 0.2f);
            al = expf(ev) / denom[d * 2 + hd];
        }
        sAl[le * 2 + hd] = al;
    }
    __syncthreads();

    // phase 1: t = lrelu(LN(A[src]+B[dst]+b1), 0.2) -> bf16 LDS (XOR-swizzled cols)
    const int wv = tid >> 6, ln = tid & 63;
    for (int j = 0; j < 8; ++j) {
        int e = wv * 8 + j;
        if (e < nev) {
            int s = sS[e], d = sD[e];
            float2 av = *(const float2*)&Abuf[(size_t)s * 128 + ln * 2];
            float2 bv = *(const float2*)&Bbuf[(size_t)d * 128 + ln * 2];
            float v0 = av.x + bv.x + sB1[ln * 2];
            float v1 = av.y + bv.y + sB1[ln * 2 + 1];
            float sm = v0 + v1, sq = v0 * v0 + v1 * v1;
#pragma unroll
            for (int m = 32; m >= 1; m >>= 1) { sm += __shfl_xor(sm, m); sq += __shfl_xor(sq, m); }
            float mean = sm * (1.f / 128.f);
            float var = sq * (1.f / 128.f) - mean * mean;
            float inv = rsqrtf(var + LNEPS);
            v0 = lrelu((v0 - mean) * inv * sG1[ln * 2] + sE1[ln * 2], 0.2f);
            v1 = lrelu((v1 - mean) * inv * sG1[ln * 2 + 1] + sE1[ln * 2 + 1], 0.2f);
            sT32[e * 64 + (ln ^ ((e & 15) << 2))] = pack_bf2(v0, v1);
        }
    }
    __syncthreads();

    // phase 2: u = t @ W2 via MFMA. 8 waves, each one 32x32 output tile.
    {
        const int w = wv, l = ln;
        const int m0 = (w >> 2) * 32, n0 = (w & 3) * 32;
        f32x16 acc = {};
#pragma unroll
        for (int ks = 0; ks < 8; ++ks) {
            int row = m0 + (l & 31);
            int colu = (ks * 8 + (l >> 5) * 4) ^ ((row & 15) << 2);
            short8 a = *(const short8*)&sT32[row * 64 + colu];
            short8 b = *(const short8*)&sWB[((((w & 3) * 8 + ks) * 64 + l)) * 4];
            acc = __builtin_amdgcn_mfma_f32_32x32x16_bf16(a, b, acc, 0, 0, 0);
        }
        __syncthreads();   // all waves done reading sWB before overwriting as sU
        float b2c = sB2[n0 + (l & 31)];
#pragma unroll
        for (int r = 0; r < 16; ++r) {
            int row = m0 + (r & 3) + 8 * (r >> 2) + 4 * (l >> 5);
            sU[row * 128 + n0 + (l & 31)] = acc[r] + b2c;
        }
    }
    __syncthreads();

    // phase 3: LN(u)+lrelu, *edge_attr, + GAT ht[src]*alpha; run-merged atomic scatter
    {
        int curd = -1;
        float acc0 = 0.f, acc1 = 0.f;
        for (int j = 0; j < 8; ++j) {
            int e = wv * 8 + j;
            if (e >= nev) break;
            int s = sS[e], d = sD[e];
            float2 uv = *(const float2*)&sU[e * 128 + ln * 2];
            float u0 = uv.x, u1 = uv.y;
            float sm = u0 + u1, sq = u0 * u0 + u1 * u1;
#pragma unroll
            for (int m = 32; m >= 1; m >>= 1) { sm += __shfl_xor(sm, m); sq += __shfl_xor(sq, m); }
            float mean = sm * (1.f / 128.f);
            float var = sq * (1.f / 128.f) - mean * mean;
            float inv = rsqrtf(var + LNEPS);
            float eav = sEA[e];
            float v0 = lrelu((u0 - mean) * inv * sG2[ln * 2] + sE2[ln * 2], 0.2f) * eav;
            float v1 = lrelu((u1 - mean) * inv * sG2[ln * 2 + 1] + sE2[ln * 2 + 1], 0.2f) * eav;
            float al = sAl[e * 2 + (ln >> 5)];
            float2 hv = *(const float2*)&ht[(size_t)s * 128 + ln * 2];
            v0 += hv.x * al;
            v1 += hv.y * al;
            if (d != curd) {
                if (curd >= 0) {
                    atomicAdd(&xsum[(size_t)curd * 128 + ln * 2], acc0);
                    atomicAdd(&xsum[(size_t)curd * 128 + ln * 2 + 1], acc1);
                }
                curd = d; acc0 = v0; acc1 = v1;
            } else { acc0 += v0; acc1 += v1; }
        }
        if (curd >= 0) {
            atomicAdd(&xsum[(size_t)curd * 128 + ln * 2], acc0);
            atomicAdd(&xsum[(size_t)curd * 128 + ln * 2 + 1], acc1);
        }
    }
}

// ---- h = lrelu(LN(xsum)) (+ x0 residual, update x0) ----
__global__ __launch_bounds__(128) void k_norm(const float* __restrict__ xsum,
                                              const float* __restrict__ g,
                                              const float* __restrict__ b,
                                              float* __restrict__ x0,
                                              float* __restrict__ h, int n, int layer)
{
    __shared__ float red[4];
    int node = blockIdx.x, c = threadIdx.x;
    float v = xsum[(size_t)node * 128 + c];
    float mean, inv;
    ln_stats128(v, red, mean, inv);
    float val = lrelu((v - mean) * inv * g[c] + b[c], 0.01f);
    if (layer > 0) {
        val += x0[(size_t)node * 128 + c];
        x0[(size_t)node * 128 + c] = val;
    }
    h[(size_t)node * 128 + c] = val;
}

// ---- pooling attention scores (one node per wave) ----
__global__ __launch_bounds__(256) void k_pool_score(const float* __restrict__ h,
    const float* __restrict__ w1, const float* __restrict__ b1,
    const float* __restrict__ w2, const float* __restrict__ b2,
    float* __restrict__ score, int n)
{
    int wv = threadIdx.x >> 6, ln = threadIdx.x & 63;
    int node = blockIdx.x * 4 + wv;
    if (node >= n) return;
    float acc = b1[ln];
    const float* hr = h + (size_t)node * 128;
    for (int k = 0; k < 128; ++k) acc += hr[k] * w1[k * 64 + ln];
    acc = lrelu(acc, 0.01f) * w2[ln];
#pragma unroll
    for (int m = 32; m >= 1; m >>= 1) acc += __shfl_xor(acc, m);
    if (ln == 0) score[node] = acc + b2[0];
}

// ---- softmax stats (single block) + zero gf ----
__global__ __launch_bounds__(256) void k_softmax_reduce(const float* __restrict__ score,
                                                        float* __restrict__ stats,
                                                        float* __restrict__ gf, int n)
{
    __shared__ float red[8];
    int t = threadIdx.x;
    float mx = -1e30f;
    for (int i = t; i < n; i += 256) mx = fmaxf(mx, score[i]);
#pragma unroll
    for (int m = 32; m >= 1; m >>= 1) mx = fmaxf(mx, __shfl_xor(mx, m));
    if ((t & 63) == 0) red[t >> 6] = mx;
    __syncthreads();
    mx = fmaxf(fmaxf(red[0], red[1]), fmaxf(red[2], red[3]));
    float s = 0.f;
    for (int i = t; i < n; i += 256) s += expf(score[i] - mx);
#pragma unroll
    for (int m = 32; m >= 1; m >>= 1) s += __shfl_xor(s, m);
    if ((t & 63) == 0) red[4 + (t >> 6)] = s;
    __syncthreads();
    s = red[4] + red[5] + red[6] + red[7];
    if (t == 0) { stats[0] = mx; stats[1] = s; }
    if (t < 128) gf[t] = 0.f;
}

// ---- gf = sum_n softmax(score)[n] * h[n,:] ----
__global__ __launch_bounds__(128) void k_gf(const float* __restrict__ h,
                                            const float* __restrict__ score,
                                            const float* __restrict__ stats,
                                            float* __restrict__ gf, int n)
{
    int c = threadIdx.x;
    float mx = stats[0], invZ = 1.f / stats[1];
    int per = (n + gridDim.x - 1) / gridDim.x;
    int n0 = blockIdx.x * per;
    int n1 = n0 + per; if (n1 > n) n1 = n;
    float acc = 0.f;
    for (int i = n0; i < n1; ++i)
        acc += expf(score[i] - mx) * invZ * h[(size_t)i * 128 + c];
    atomicAdd(&gf[c], acc);
}

// ---- final head (single 128-thread block) ----
__global__ __launch_bounds__(128) void k_head(
    const float* __restrict__ gf, const float* __restrict__ tf,
    const float* __restrict__ task_w, const float* __restrict__ task_b,
    const float* __restrict__ task_g, const float* __restrict__ task_be,
    const float* __restrict__ v_w1, const float* __restrict__ v_b1,
    const float* __restrict__ v_g, const float* __restrict__ v_be,
    const float* __restrict__ v_w2, const float* __restrict__ v_b2,
    const float* __restrict__ a_w1, const float* __restrict__ a_b1,
    const float* __restrict__ a_g, const float* __restrict__ a_be,
    const float* __restrict__ a_w2, const float* __restrict__ a_b2,
    float* __restrict__ out)
{
    __shared__ float cf[256], hbuf[128], red[4], sc[2], adv[10];
    int t = threadIdx.x;
    float mean, inv;
    // task embedding
    float te = task_b[t];
#pragma unroll
    for (int k = 0; k < 4; ++k) te += tf[k] * task_w[k * 128 + t];
    ln_stats128(te, red, mean, inv);
    te = lrelu((te - mean) * inv * task_g[t] + task_be[t], 0.01f);
    cf[t] = gf[t]; cf[128 + t] = te;
    __syncthreads();
    // value branch
    float v = v_b1[t];
    for (int k = 0; k < 256; ++k) v += cf[k] * v_w1[k * 128 + t];
    ln_stats128(v, red, mean, inv);
    v = lrelu((v - mean) * inv * v_g[t] + v_be[t], 0.01f);
    float pv = v * v_w2[t];
#pragma unroll
    for (int m = 32; m >= 1; m >>= 1) pv += __shfl_xor(pv, m);
    __syncthreads();
    if ((t & 63) == 0) red[t >> 6] = pv;
    __syncthreads();
    if (t == 0) sc[0] = red[0] + red[1] + v_b2[0];
    // advantage branch
    float a = a_b1[t];
    for (int k = 0; k < 256; ++k) a += cf[k] * a_w1[k * 128 + t];
    ln_stats128(a, red, mean, inv);
    a = lrelu((a - mean) * inv * a_g[t] + a_be[t], 0.01f);
    hbuf[t] = a;
    __syncthreads();
    if (t < 10) {
        float s = a_b2[t];
        for (int c = 0; c < 128; ++c) s += hbuf[c] * a_w2[c * 10 + t];
        adv[t] = s;
    }
    __syncthreads();
    if (t == 0) {
        float m10 = 0.f;
        for (int o = 0; o < 10; ++o) m10 += adv[o];
        sc[1] = m10 * 0.1f;
    }
    __syncthreads();
    if (t < 10) out[t] = sc[0] + adv[t] - sc[1];
}

extern "C" void kernel_launch(void* const* d_in, const int* in_sizes, int n_in,
                              void* d_out, int out_size, void* d_ws, size_t ws_size,
                              hipStream_t stream)
{
    const float* x        = (const float*)d_in[0];
    const int*   ei       = (const int*)d_in[1];
    const float* ea       = (const float*)d_in[2];
    const float* tf       = (const float*)d_in[3];
    const float* emb_w    = (const float*)d_in[4];
    const float* emb_b    = (const float*)d_in[5];
    const float* emb_g    = (const float*)d_in[6];
    const float* emb_beta = (const float*)d_in[7];
    const float* gat_w    = (const float*)d_in[8];
    const float* gat_as   = (const float*)d_in[9];
    const float* gat_ad   = (const float*)d_in[10];
    const float* gat_bias = (const float*)d_in[11];
    const float* ec_w1    = (const float*)d_in[12];
    const float* ec_b1    = (const float*)d_in[13];
    const float* ec_g1    = (const float*)d_in[14];
    const float* ec_be1   = (const float*)d_in[15];
    const float* ec_w2    = (const float*)d_in[16];
    const float* ec_b2    = (const float*)d_in[17];
    const float* ec_g2    = (const float*)d_in[18];
    const float* ec_be2   = (const float*)d_in[19];
    const float* norm_g   = (const float*)d_in[20];
    const float* norm_b   = (const float*)d_in[21];
    const float* task_w   = (const float*)d_in[22];
    const float* task_b   = (const float*)d_in[23];
    const float* task_g   = (const float*)d_in[24];
    const float* task_be  = (const float*)d_in[25];
    const float* pa_w1    = (const float*)d_in[26];
    const float* pa_b1    = (const float*)d_in[27];
    const float* pa_w2    = (const float*)d_in[28];
    const float* pa_b2    = (const float*)d_in[29];
    const float* v_w1     = (const float*)d_in[30];
    const float* v_b1     = (const float*)d_in[31];
    const float* v_g      = (const float*)d_in[32];
    const float* v_be     = (const float*)d_in[33];
    const float* v_w2     = (const float*)d_in[34];
    const float* v_b2     = (const float*)d_in[35];
    const float* a_w1     = (const float*)d_in[36];
    const float* a_b1     = (const float*)d_in[37];
    const float* a_g      = (const float*)d_in[38];
    const float* a_be     = (const float*)d_in[39];
    const float* a_w2     = (const float*)d_in[40];
    const float* a_b2     = (const float*)d_in[41];

    const int n = in_sizes[0] / 128;   // 25000
    const int e = in_sizes[2];         // 400000
    const int* src = ei;
    const int* dst = ei + e;

    float* ws = (float*)d_ws;
    const size_t NR = (size_t)n * 128;
    float* h    = ws;
    float* x0   = ws + NR;
    float* ht   = ws + 2 * NR;
    float* A    = ws + 3 * NR;
    float* B    = ws + 4 * NR;
    float* xs   = ws + 5 * NR;
    float* a_s  = ws + 6 * NR;
    float* a_d  = a_s + (size_t)n * 2;
    float* den  = a_d + (size_t)n * 2;
    float* score = den + (size_t)n * 2;
    float* stats = score + n;
    float* gf    = stats + 2;
    // sorted-edge buffers
    int*   cnt    = (int*)(gf + 128);
    int*   starts = cnt + n;
    int*   s_src  = starts + (n + 1);
    int*   s_dst  = s_src + e;
    float* s_ea   = (float*)(s_dst + e);

    const int ngb = (n + GROWS - 1) / GROWS;

    // ---- one-time: counting-sort edges by dst ----
    hipMemsetAsync(cnt, 0, (size_t)n * sizeof(int), stream);
    k_hist<<<(e + 255) / 256, 256, 0, stream>>>(dst, cnt, e);
    k_scan<<<1, 1024, 0, stream>>>(cnt, starts, n);
    hipMemcpyAsync(cnt, starts, (size_t)n * sizeof(int), hipMemcpyDeviceToDevice, stream);
    k_scatter<<<(e + 255) / 256, 256, 0, stream>>>(src, dst, ea, cnt, s_src, s_dst, s_ea, e);

    // embedding: h = lrelu(LN(x @ emb_w + emb_b)), x0 = h
    k_node_gemm<<<ngb, 256, 0, stream>>>(x, emb_w, emb_b, emb_g, emb_beta, h, x0, n, 1, 0.01f);

    for (int i = 0; i < LL; ++i) {
        k_node_gemm<<<ngb, 256, 0, stream>>>(h, gat_w + (size_t)i * 16384,
                                             nullptr, nullptr, nullptr, ht, nullptr, n, 0, 0.f);
        k_gat_scores<<<(n * 2 + 255) / 256, 256, 0, stream>>>(ht, gat_as + i * 128, gat_ad + i * 128,
                                                              a_s, a_d, n);
        k_node_gemm<<<ngb, 256, 0, stream>>>(h, ec_w1 + (size_t)i * 32768,
                                             nullptr, nullptr, nullptr, A, nullptr, n, 0, 0.f);
        k_node_gemm<<<ngb, 256, 0, stream>>>(h, ec_w1 + (size_t)i * 32768 + 16384,
                                             nullptr, nullptr, nullptr, B, nullptr, n, 0, 0.f);
        k_denom_init<<<(n * 2 + 255) / 256, 256, 0, stream>>>(a_s, a_d, den, n);
        k_edge_denom2<<<((e + 7) / 8 + 255) / 256, 256, 0, stream>>>(s_src, s_dst, a_s, a_d, den, e);
        k_xsum_init<<<(n * 128 + 255) / 256, 256, 0, stream>>>(ht, a_s, a_d, den,
                                                               gat_bias + i * 128, xs, n);
        k_edge_main<<<(e + EB - 1) / EB, 512, 0, stream>>>(A, B, ht, s_src, s_dst, s_ea,
                                                           a_s, a_d, den,
                                                           ec_w2 + (size_t)i * 16384,
                                                           ec_b1 + i * 128, ec_g1 + i * 128, ec_be1 + i * 128,
                                                           ec_b2 + i * 128, ec_g2 + i * 128, ec_be2 + i * 128,
                                                           xs, e);
        k_norm<<<n, 128, 0, stream>>>(xs, norm_g + i * 128, norm_b + i * 128, x0, h, n, i);
    }

    k_pool_score<<<(n + 3) / 4, 256, 0, stream>>>(h, pa_w1, pa_b1, pa_w2, pa_b2, score, n);
    k_softmax_reduce<<<1, 256, 0, stream>>>(score, stats, gf, n);
    k_gf<<<200, 128, 0, stream>>>(h, score, stats, gf, n);
    k_head<<<1, 128, 0, stream>>>(gf, tf, task_w, task_b, task_g, task_be,
                                  v_w1, v_b1, v_g, v_be, v_w2, v_b2,
                                  a_w1, a_b1, a_g, a_be, a_w2, a_b2,
                                  (float*)d_out);
}

// Round 4
// 831.338 us; speedup vs baseline: 2.0974x; 1.2293x over previous
//
#include <hip/hip_runtime.h>
#include <math.h>

#define NN 25000
#define EE 400000
#define LL 3
#define LNEPS 1e-5f
#define GROWS 32
#define EB 64

typedef __attribute__((ext_vector_type(8))) short short8;
typedef __attribute__((ext_vector_type(16))) float f32x16;

__device__ __forceinline__ float lrelu(float x, float s) { return fmaxf(x, x * s); }

__device__ __forceinline__ unsigned int pack_bf2(float lo, float hi) {
    unsigned int ul = __float_as_uint(lo), uh = __float_as_uint(hi);
    ul = (ul + 0x7FFFu + ((ul >> 16) & 1u)) >> 16;
    uh = (uh + 0x7FFFu + ((uh >> 16) & 1u)) >> 16;
    return (uh << 16) | (ul & 0xFFFFu);
}

// 128-thread block LN stats (2 waves)
__device__ __forceinline__ void ln_stats128(float v, float* red, float& mean, float& inv) {
    float sm = v, sq = v * v;
#pragma unroll
    for (int m = 32; m >= 1; m >>= 1) { sm += __shfl_xor(sm, m); sq += __shfl_xor(sq, m); }
    __syncthreads();
    if ((threadIdx.x & 63) == 0) { red[(threadIdx.x >> 6) * 2] = sm; red[(threadIdx.x >> 6) * 2 + 1] = sq; }
    __syncthreads();
    sm = red[0] + red[2]; sq = red[1] + red[3];
    mean = sm * (1.f / 128.f);
    float var = sq * (1.f / 128.f) - mean * mean;
    inv = rsqrtf(var + LNEPS);
}

// ================= edge sorting (counting sort by dst) =================
__global__ void k_hist(const int* __restrict__ dst, int* __restrict__ cnt, int ne)
{
    int i = blockIdx.x * 256 + threadIdx.x;
    if (i < ne) atomicAdd(&cnt[dst[i]], 1);
}

__global__ __launch_bounds__(1024) void k_scan(const int* __restrict__ cnt,
                                               int* __restrict__ starts, int n)
{
    __shared__ int tot[1024];
    int t = threadIdx.x;
    const int PER = (n + 1023) >> 10;
    int i0 = t * PER;
    int s = 0;
    for (int k = 0; k < PER; ++k) { int i = i0 + k; s += (i < n) ? cnt[i] : 0; }
    tot[t] = s;
    __syncthreads();
    for (int off = 1; off < 1024; off <<= 1) {
        int x = (t >= off) ? tot[t - off] : 0;
        __syncthreads();
        tot[t] += x;
        __syncthreads();
    }
    int run = (t > 0) ? tot[t - 1] : 0;
    for (int k = 0; k < PER; ++k) {
        int i = i0 + k;
        if (i < n) { starts[i] = run; run += cnt[i]; }
    }
    if (t == 1023) starts[n] = tot[1023];
}

__global__ void k_scatter(const int* __restrict__ src, const int* __restrict__ dst,
                          const float* __restrict__ ea, int* __restrict__ cursor,
                          int* __restrict__ s_src, int* __restrict__ s_dst,
                          float* __restrict__ s_ea, int ne)
{
    int i = blockIdx.x * 256 + threadIdx.x;
    if (i >= ne) return;
    int d = dst[i];
    int pos = atomicAdd(&cursor[d], 1);
    s_src[pos] = src[i];
    s_dst[pos] = d;
    s_ea[pos] = ea[i];
}

// ================= weight pre-pack: fp32 [128x128] -> bf16 B-fragment order =================
// mat m: 0..2 = gat_w[i]; 3..8 = ec_w1 layer (m-3)>>1, half (m-3)&1; 9..11 = ec_w2[i]
__global__ void k_prep(const float* __restrict__ gat_w, const float* __restrict__ ec_w1,
                       const float* __restrict__ ec_w2, uint4* __restrict__ wf)
{
    int g = blockIdx.x * 256 + threadIdx.x;   // < 12*2048
    int m = g >> 11, f = g & 2047;
    const float* srcm;
    if (m < 3) srcm = gat_w + (size_t)m * 16384;
    else if (m < 9) { int t2 = m - 3; srcm = ec_w1 + (size_t)(t2 >> 1) * 32768 + (size_t)(t2 & 1) * 16384; }
    else srcm = ec_w2 + (size_t)(m - 9) * 16384;
    int l = f & 63, ks = (f >> 6) & 7, nb = f >> 9;
    int k0 = ks * 16 + (l >> 5) * 8, col = nb * 32 + (l & 31);
    const float* wp = srcm + (size_t)k0 * 128 + col;
    uint4 r;
    r.x = pack_bf2(wp[0],   wp[128]);
    r.y = pack_bf2(wp[256], wp[384]);
    r.z = pack_bf2(wp[512], wp[640]);
    r.w = pack_bf2(wp[768], wp[896]);
    wf[g] = r;
}

// ---- scalar node GEMM (kept for embedding with fused LN) ----
__global__ __launch_bounds__(256) void k_node_gemm(
    const float* __restrict__ in, const float* __restrict__ W,
    const float* __restrict__ bias, const float* __restrict__ g,
    const float* __restrict__ be, float* __restrict__ out,
    float* __restrict__ out2, int nrows, int do_ln, float slope)
{
    __shared__ float sW[128 * 128];
    __shared__ float sIn[GROWS * 128];
    const int tid = threadIdx.x;
    {
        const float4* W4 = (const float4*)W;
        float4* sW4 = (float4*)sW;
#pragma unroll
        for (int i = 0; i < 16; ++i) sW4[tid + 256 * i] = W4[tid + 256 * i];
    }
    const int r0 = blockIdx.x * GROWS;
    {
        const float4* in4 = (const float4*)in;
        float4* sIn4 = (float4*)sIn;
#pragma unroll
        for (int i = 0; i < 4; ++i) {
            int idx = tid + 256 * i;
            int row = idx >> 5;
            sIn4[idx] = (r0 + row < nrows) ? in4[(size_t)r0 * 32 + idx]
                                           : make_float4(0.f, 0.f, 0.f, 0.f);
        }
    }
    __syncthreads();
    const int rt = tid >> 5, ct = tid & 31;
    float acc[4][4];
#pragma unroll
    for (int i = 0; i < 4; ++i) acc[i][0] = acc[i][1] = acc[i][2] = acc[i][3] = 0.f;
#pragma unroll 4
    for (int k = 0; k < 128; ++k) {
        float4 wv = *(const float4*)&sW[k * 128 + ct * 4];
#pragma unroll
        for (int i = 0; i < 4; ++i) {
            float a = sIn[(rt * 4 + i) * 128 + k];
            acc[i][0] += a * wv.x; acc[i][1] += a * wv.y;
            acc[i][2] += a * wv.z; acc[i][3] += a * wv.w;
        }
    }
    if (!do_ln) {
#pragma unroll
        for (int i = 0; i < 4; ++i) {
            int row = r0 + rt * 4 + i;
            if (row < nrows)
                *(float4*)&out[(size_t)row * 128 + ct * 4] =
                    make_float4(acc[i][0], acc[i][1], acc[i][2], acc[i][3]);
        }
    } else {
        float4 bv = *(const float4*)&bias[ct * 4];
        float4 gv = *(const float4*)&g[ct * 4];
        float4 ev = *(const float4*)&be[ct * 4];
        float rs[4], rq[4];
#pragma unroll
        for (int i = 0; i < 4; ++i) {
            acc[i][0] += bv.x; acc[i][1] += bv.y; acc[i][2] += bv.z; acc[i][3] += bv.w;
            rs[i] = acc[i][0] + acc[i][1] + acc[i][2] + acc[i][3];
            rq[i] = acc[i][0] * acc[i][0] + acc[i][1] * acc[i][1]
                  + acc[i][2] * acc[i][2] + acc[i][3] * acc[i][3];
        }
#pragma unroll
        for (int m = 16; m >= 1; m >>= 1) {
#pragma unroll
            for (int i = 0; i < 4; ++i) { rs[i] += __shfl_xor(rs[i], m); rq[i] += __shfl_xor(rq[i], m); }
        }
#pragma unroll
        for (int i = 0; i < 4; ++i) {
            int row = r0 + rt * 4 + i;
            float mean = rs[i] * (1.f / 128.f);
            float var = rq[i] * (1.f / 128.f) - mean * mean;
            float inv = rsqrtf(var + LNEPS);
            float4 o;
            o.x = lrelu((acc[i][0] - mean) * inv * gv.x + ev.x, slope);
            o.y = lrelu((acc[i][1] - mean) * inv * gv.y + ev.y, slope);
            o.z = lrelu((acc[i][2] - mean) * inv * gv.z + ev.z, slope);
            o.w = lrelu((acc[i][3] - mean) * inv * gv.w + ev.w, slope);
            if (row < nrows) {
                *(float4*)&out[(size_t)row * 128 + ct * 4] = o;
                if (out2) *(float4*)&out2[(size_t)row * 128 + ct * 4] = o;
            }
        }
    }
}

// ---- MFMA 3-in-1 node GEMM: {ht, A'(+b1), B} = h @ {Wht, WA, WB} ----
__global__ __launch_bounds__(256) void k_gemm3(
    const float* __restrict__ in, const uint4* __restrict__ wf,
    int mht, int mA, int mB, const float* __restrict__ bA,
    float* __restrict__ o0, float* __restrict__ o1, float* __restrict__ o2,
    int nrows)
{
    __shared__ __align__(16) unsigned int sA[64 * 64];     // 16KB bf16 tile, XOR-swizzled
    __shared__ __align__(16) unsigned int sW[2048 * 4];    // 32KB B-fragments
    const int tid = threadIdx.x;
    const int r0 = blockIdx.x * 64;
    {   // stage A: 64 rows x 128 cols fp32 -> bf16 pairs
        int row = tid >> 2, q = tid & 3;
        const float* srcp = in + (size_t)(r0 + row) * 128 + q * 32;
        bool ok = (r0 + row) < nrows;
#pragma unroll
        for (int i = 0; i < 8; ++i) {
            float4 v = ok ? *(const float4*)&srcp[i * 4] : make_float4(0.f, 0.f, 0.f, 0.f);
            unsigned int p0 = pack_bf2(v.x, v.y), p1 = pack_bf2(v.z, v.w);
            int cu = (q * 16 + i * 2) ^ ((row & 15) << 2);
            *(uint2*)&sA[row * 64 + cu] = make_uint2(p0, p1);
        }
    }
    __syncthreads();
    const int w = tid >> 6, l = tid & 63;
    const int m0 = (w >> 1) * 32, nhalf = (w & 1);
    short8 af[8];
#pragma unroll
    for (int ks = 0; ks < 8; ++ks) {
        int row = m0 + (l & 31);
        int cu = (ks * 8 + (l >> 5) * 4) ^ ((row & 15) << 2);
        af[ks] = *(const short8*)&sA[row * 64 + cu];
    }
    auto do_mat = [&](int mat, float* out, const float* bp) {
        __syncthreads();
        {
            const uint4* wsrc = wf + (size_t)mat * 2048;
            uint4* sW4 = (uint4*)sW;
#pragma unroll
            for (int i = 0; i < 8; ++i) sW4[tid + 256 * i] = wsrc[tid + 256 * i];
        }
        __syncthreads();
        f32x16 acc0 = {}, acc1 = {};
        const int nb0 = nhalf * 2;
#pragma unroll
        for (int ks = 0; ks < 8; ++ks) {
            short8 b0 = *(const short8*)&sW[((nb0 * 8 + ks) * 64 + l) * 4];
            short8 b1v = *(const short8*)&sW[(((nb0 + 1) * 8 + ks) * 64 + l) * 4];
            acc0 = __builtin_amdgcn_mfma_f32_32x32x16_bf16(af[ks], b0, acc0, 0, 0, 0);
            acc1 = __builtin_amdgcn_mfma_f32_32x32x16_bf16(af[ks], b1v, acc1, 0, 0, 0);
        }
        int colbase = nhalf * 64 + (l & 31);
        float badd0 = bp ? bp[colbase] : 0.f;
        float badd1 = bp ? bp[colbase + 32] : 0.f;
#pragma unroll
        for (int r = 0; r < 16; ++r) {
            int row = r0 + m0 + (r & 3) + 8 * (r >> 2) + 4 * (l >> 5);
            if (row < nrows) {
                out[(size_t)row * 128 + colbase]      = acc0[r] + badd0;
                out[(size_t)row * 128 + colbase + 32] = acc1[r] + badd1;
            }
        }
    };
    do_mat(mht, o0, nullptr);
    do_mat(mA, o1, bA);
    do_mat(mB, o2, nullptr);
}

// ---- GAT scores + self-loop denom init ----
__global__ void k_gat_scores(const float* __restrict__ ht, const float* __restrict__ as_,
                             const float* __restrict__ ad_, float* __restrict__ a_s,
                             float* __restrict__ a_d, float* __restrict__ denom,
                             float* __restrict__ selfe, int n)
{
    int idx = blockIdx.x * blockDim.x + threadIdx.x;
    if (idx >= n * 2) return;
    int node = idx >> 1, hd = idx & 1;
    const float4* row = (const float4*)(ht + (size_t)node * 128 + hd * 64);
    const float4* wsv = (const float4*)(as_ + hd * 64);
    const float4* wdv = (const float4*)(ad_ + hd * 64);
    float ss = 0.f, sd = 0.f;
#pragma unroll
    for (int i = 0; i < 16; ++i) {
        float4 v = row[i], vs = wsv[i], vd = wdv[i];
        ss += v.x * vs.x + v.y * vs.y + v.z * vs.z + v.w * vs.w;
        sd += v.x * vd.x + v.y * vd.y + v.z * vd.z + v.w * vd.w;
    }
    a_s[idx] = ss; a_d[idx] = sd;
    float ev = expf(lrelu(ss + sd, 0.2f));
    denom[idx] = ev;
    selfe[idx] = ev;
}

// ---- per-node row sums of A' and B ----
__global__ __launch_bounds__(512) void k_rowsums(const float* __restrict__ A,
                                                 const float* __restrict__ B,
                                                 float* __restrict__ rsA,
                                                 float* __restrict__ rsB, int n)
{
    int wv = threadIdx.x >> 6, ln = threadIdx.x & 63;
    int node = blockIdx.x * 8 + wv;
    if (node >= n) return;
    float2 a = *(const float2*)&A[(size_t)node * 128 + ln * 2];
    float2 b = *(const float2*)&B[(size_t)node * 128 + ln * 2];
    float sa = a.x + a.y, sb = b.x + b.y;
#pragma unroll
    for (int m = 32; m >= 1; m >>= 1) { sa += __shfl_xor(sa, m); sb += __shfl_xor(sb, m); }
    if (ln == 0) { rsA[node] = sa; rsB[node] = sb; }
}

// ---- accumulate exp(e) per dst over sorted edges, run-merged ----
__global__ void k_edge_denom2(const int* __restrict__ s_src, const int* __restrict__ s_dst,
                              const float* __restrict__ a_s, const float* __restrict__ a_d,
                              float* __restrict__ denom, int ne)
{
    int base = (blockIdx.x * 256 + threadIdx.x) * 8;
    if (base >= ne) return;
    int curd = -1;
    float acc0 = 0.f, acc1 = 0.f;
    for (int k = 0; k < 8; ++k) {
        int e = base + k;
        if (e >= ne) break;
        int s = s_src[e], d = s_dst[e];
        float v0 = expf(lrelu(a_s[s * 2]     + a_d[d * 2],     0.2f));
        float v1 = expf(lrelu(a_s[s * 2 + 1] + a_d[d * 2 + 1], 0.2f));
        if (d != curd) {
            if (curd >= 0) { atomicAdd(&denom[curd * 2], acc0); atomicAdd(&denom[curd * 2 + 1], acc1); }
            curd = d; acc0 = v0; acc1 = v1;
        } else { acc0 += v0; acc1 += v1; }
    }
    if (curd >= 0) { atomicAdd(&denom[curd * 2], acc0); atomicAdd(&denom[curd * 2 + 1], acc1); }
}

// ---- xsum = gat_bias + self-loop GAT contribution ----
__global__ void k_xsum_init(const float* __restrict__ ht, const float* __restrict__ selfe,
                            const float* __restrict__ denom,
                            const float* __restrict__ gbias, float* __restrict__ xsum, int n)
{
    int idx = blockIdx.x * blockDim.x + threadIdx.x;
    if (idx >= n * 128) return;
    int node = idx >> 7, c = idx & 127, hd = c >> 6;
    float alpha = selfe[node * 2 + hd] / denom[node * 2 + hd];
    xsum[idx] = gbias[c] + ht[idx] * alpha;
}

// ---- fused edge kernel (dst-sorted): EdgeConv MLP (MFMA) + GAT, run-merged scatter ----
__global__ __launch_bounds__(512) void k_edge_main(
    const float* __restrict__ Abuf, const float* __restrict__ Bbuf,
    const float* __restrict__ ht,
    const int* __restrict__ s_src, const int* __restrict__ s_dst,
    const float* __restrict__ s_ea,
    const float* __restrict__ a_s, const float* __restrict__ a_d,
    const float* __restrict__ denom,
    const uint4* __restrict__ w2f,
    const float* __restrict__ rsA, const float* __restrict__ rsB,
    const float* __restrict__ g1, const float* __restrict__ be1,
    const float* __restrict__ b2, const float* __restrict__ g2, const float* __restrict__ be2,
    float* __restrict__ xsum, int ne)
{
    // sWB: W2 bf16 B-fragments (32KB); reused after phase 2 as fp32 sU[64][128].
    __shared__ __align__(16) unsigned int sWB[2048 * 4];
    __shared__ __align__(16) unsigned int sT32[EB * 64];   // t tile bf16 pairs, XOR-swizzled
    __shared__ int   sS[EB], sD[EB];
    __shared__ float sEA[EB], sM[EB];
    __shared__ float sAl[EB * 2];
    __shared__ float sG1[128], sE1[128], sB2[128], sG2[128], sE2[128];
    float* sU = (float*)sWB;

    const int tid = threadIdx.x;
    {   // stage W2 fragments: pure copy (pre-packed by k_prep)
        uint4* sWB4 = (uint4*)sWB;
#pragma unroll
        for (int i = 0; i < 4; ++i) { int f = tid + 512 * i; sWB4[f] = w2f[f]; }
    }
    if (tid < 128) {
        sG1[tid] = g1[tid]; sE1[tid] = be1[tid];
        sB2[tid] = b2[tid]; sG2[tid] = g2[tid]; sE2[tid] = be2[tid];
    }
    const int e0 = blockIdx.x * EB;
    const int nev = (ne - e0 < EB) ? (ne - e0) : EB;
    if (tid < EB) {
        if (tid < nev) {
            int s = s_src[e0 + tid], d = s_dst[e0 + tid];
            sS[tid] = s; sD[tid] = d; sEA[tid] = s_ea[e0 + tid];
            sM[tid] = (rsA[s] + rsB[d]) * (1.f / 128.f);
        } else { sS[tid] = 0; sD[tid] = -1; sEA[tid] = 0.f; sM[tid] = 0.f; }
    }
    if (tid < 2 * EB) {
        int le = tid >> 1, hd = tid & 1;
        float al = 0.f;
        if (le < nev) {
            int e = e0 + le;
            int s = s_src[e], d = s_dst[e];
            float ev = lrelu(a_s[s * 2 + hd] + a_d[d * 2 + hd], 0.2f);
            al = expf(ev) / denom[d * 2 + hd];
        }
        sAl[le * 2 + hd] = al;
    }
    __syncthreads();

    // phase 1: t = lrelu(LN(A'[src]+B[dst]), 0.2) -> bf16 LDS (mean precomputed)
    const int wv = tid >> 6, ln = tid & 63;
    for (int j = 0; j < 8; ++j) {
        int e = wv * 8 + j;
        if (e < nev) {
            int s = sS[e], d = sD[e];
            float mean = sM[e];
            float2 av = *(const float2*)&Abuf[(size_t)s * 128 + ln * 2];
            float2 bv = *(const float2*)&Bbuf[(size_t)d * 128 + ln * 2];
            float v0 = av.x + bv.x - mean;
            float v1 = av.y + bv.y - mean;
            float sq = v0 * v0 + v1 * v1;
#pragma unroll
            for (int m = 32; m >= 1; m >>= 1) sq += __shfl_xor(sq, m);
            float inv = rsqrtf(sq * (1.f / 128.f) + LNEPS);
            float t0 = lrelu(v0 * inv * sG1[ln * 2] + sE1[ln * 2], 0.2f);
            float t1 = lrelu(v1 * inv * sG1[ln * 2 + 1] + sE1[ln * 2 + 1], 0.2f);
            sT32[e * 64 + (ln ^ ((e & 15) << 2))] = pack_bf2(t0, t1);
        }
    }
    __syncthreads();

    // phase 2: u = t @ W2 via MFMA. 8 waves, each one 32x32 output tile.
    {
        const int w = wv, l = ln;
        const int m0 = (w >> 2) * 32, n0 = (w & 3) * 32;
        f32x16 acc = {};
#pragma unroll
        for (int ks = 0; ks < 8; ++ks) {
            int row = m0 + (l & 31);
            int colu = (ks * 8 + (l >> 5) * 4) ^ ((row & 15) << 2);
            short8 a = *(const short8*)&sT32[row * 64 + colu];
            short8 b = *(const short8*)&sWB[((((w & 3) * 8 + ks) * 64 + l)) * 4];
            acc = __builtin_amdgcn_mfma_f32_32x32x16_bf16(a, b, acc, 0, 0, 0);
        }
        __syncthreads();   // all waves done reading sWB before overwriting as sU
        float b2c = sB2[n0 + (l & 31)];
#pragma unroll
        for (int r = 0; r < 16; ++r) {
            int row = m0 + (r & 3) + 8 * (r >> 2) + 4 * (l >> 5);
            sU[row * 128 + n0 + (l & 31)] = acc[r] + b2c;
        }
    }
    __syncthreads();

    // phase 3: LN(u)+lrelu, *edge_attr, + GAT ht[src]*alpha; run-merged atomic scatter
    {
        int curd = -1;
        float acc0 = 0.f, acc1 = 0.f;
        for (int j = 0; j < 8; ++j) {
            int e = wv * 8 + j;
            if (e >= nev) break;
            int s = sS[e], d = sD[e];
            float2 uv = *(const float2*)&sU[e * 128 + ln * 2];
            float u0 = uv.x, u1 = uv.y;
            float sm = u0 + u1, sq = u0 * u0 + u1 * u1;
#pragma unroll
            for (int m = 32; m >= 1; m >>= 1) { sm += __shfl_xor(sm, m); sq += __shfl_xor(sq, m); }
            float mean = sm * (1.f / 128.f);
            float var = sq * (1.f / 128.f) - mean * mean;
            float inv = rsqrtf(var + LNEPS);
            float eav = sEA[e];
            float v0 = lrelu((u0 - mean) * inv * sG2[ln * 2] + sE2[ln * 2], 0.2f) * eav;
            float v1 = lrelu((u1 - mean) * inv * sG2[ln * 2 + 1] + sE2[ln * 2 + 1], 0.2f) * eav;
            float al = sAl[e * 2 + (ln >> 5)];
            float2 hv = *(const float2*)&ht[(size_t)s * 128 + ln * 2];
            v0 += hv.x * al;
            v1 += hv.y * al;
            if (d != curd) {
                if (curd >= 0) {
                    atomicAdd(&xsum[(size_t)curd * 128 + ln * 2], acc0);
                    atomicAdd(&xsum[(size_t)curd * 128 + ln * 2 + 1], acc1);
                }
                curd = d; acc0 = v0; acc1 = v1;
            } else { acc0 += v0; acc1 += v1; }
        }
        if (curd >= 0) {
            atomicAdd(&xsum[(size_t)curd * 128 + ln * 2], acc0);
            atomicAdd(&xsum[(size_t)curd * 128 + ln * 2 + 1], acc1);
        }
    }
}

// ---- h = lrelu(LN(xsum)) (+ x0 residual), wave-per-node ----
__global__ __launch_bounds__(512) void k_norm8(const float* __restrict__ xsum,
                                               const float* __restrict__ g,
                                               const float* __restrict__ b,
                                               float* __restrict__ x0,
                                               float* __restrict__ h, int n, int layer)
{
    int wv = threadIdx.x >> 6, ln = threadIdx.x & 63;
    int node = blockIdx.x * 8 + wv;
    if (node >= n) return;
    float2 v = *(const float2*)&xsum[(size_t)node * 128 + ln * 2];
    float sm = v.x + v.y, sq = v.x * v.x + v.y * v.y;
#pragma unroll
    for (int m = 32; m >= 1; m >>= 1) { sm += __shfl_xor(sm, m); sq += __shfl_xor(sq, m); }
    float mean = sm * (1.f / 128.f);
    float var = sq * (1.f / 128.f) - mean * mean;
    float inv = rsqrtf(var + LNEPS);
    float2 gv = *(const float2*)&g[ln * 2];
    float2 bv = *(const float2*)&b[ln * 2];
    float val0 = lrelu((v.x - mean) * inv * gv.x + bv.x, 0.01f);
    float val1 = lrelu((v.y - mean) * inv * gv.y + bv.y, 0.01f);
    if (layer > 0) {
        float2 x0v = *(const float2*)&x0[(size_t)node * 128 + ln * 2];
        val0 += x0v.x; val1 += x0v.y;
        *(float2*)&x0[(size_t)node * 128 + ln * 2] = make_float2(val0, val1);
    }
    *(float2*)&h[(size_t)node * 128 + ln * 2] = make_float2(val0, val1);
}

// ---- pooling attention scores (one node per wave) ----
__global__ __launch_bounds__(256) void k_pool_score(const float* __restrict__ h,
    const float* __restrict__ w1, const float* __restrict__ b1,
    const float* __restrict__ w2, const float* __restrict__ b2,
    float* __restrict__ score, int n)
{
    int wv = threadIdx.x >> 6, ln = threadIdx.x & 63;
    int node = blockIdx.x * 4 + wv;
    if (node >= n) return;
    float acc = b1[ln];
    const float* hr = h + (size_t)node * 128;
    for (int k = 0; k < 128; ++k) acc += hr[k] * w1[k * 64 + ln];
    acc = lrelu(acc, 0.01f) * w2[ln];
#pragma unroll
    for (int m = 32; m >= 1; m >>= 1) acc += __shfl_xor(acc, m);
    if (ln == 0) score[node] = acc + b2[0];
}

// ---- softmax stats (single block) + zero gf ----
__global__ __launch_bounds__(256) void k_softmax_reduce(const float* __restrict__ score,
                                                        float* __restrict__ stats,
                                                        float* __restrict__ gf, int n)
{
    __shared__ float red[8];
    int t = threadIdx.x;
    float mx = -1e30f;
    for (int i = t; i < n; i += 256) mx = fmaxf(mx, score[i]);
#pragma unroll
    for (int m = 32; m >= 1; m >>= 1) mx = fmaxf(mx, __shfl_xor(mx, m));
    if ((t & 63) == 0) red[t >> 6] = mx;
    __syncthreads();
    mx = fmaxf(fmaxf(red[0], red[1]), fmaxf(red[2], red[3]));
    float s = 0.f;
    for (int i = t; i < n; i += 256) s += expf(score[i] - mx);
#pragma unroll
    for (int m = 32; m >= 1; m >>= 1) s += __shfl_xor(s, m);
    if ((t & 63) == 0) red[4 + (t >> 6)] = s;
    __syncthreads();
    s = red[4] + red[5] + red[6] + red[7];
    if (t == 0) { stats[0] = mx; stats[1] = s; }
    if (t < 128) gf[t] = 0.f;
}

// ---- gf = sum_n softmax(score)[n] * h[n,:] ----
__global__ __launch_bounds__(128) void k_gf(const float* __restrict__ h,
                                            const float* __restrict__ score,
                                            const float* __restrict__ stats,
                                            float* __restrict__ gf, int n)
{
    int c = threadIdx.x;
    float mx = stats[0], invZ = 1.f / stats[1];
    int per = (n + gridDim.x - 1) / gridDim.x;
    int n0 = blockIdx.x * per;
    int n1 = n0 + per; if (n1 > n) n1 = n;
    float acc = 0.f;
    for (int i = n0; i < n1; ++i)
        acc += expf(score[i] - mx) * invZ * h[(size_t)i * 128 + c];
    atomicAdd(&gf[c], acc);
}

// ---- final head (single 128-thread block) ----
__global__ __launch_bounds__(128) void k_head(
    const float* __restrict__ gf, const float* __restrict__ tf,
    const float* __restrict__ task_w, const float* __restrict__ task_b,
    const float* __restrict__ task_g, const float* __restrict__ task_be,
    const float* __restrict__ v_w1, const float* __restrict__ v_b1,
    const float* __restrict__ v_g, const float* __restrict__ v_be,
    const float* __restrict__ v_w2, const float* __restrict__ v_b2,
    const float* __restrict__ a_w1, const float* __restrict__ a_b1,
    const float* __restrict__ a_g, const float* __restrict__ a_be,
    const float* __restrict__ a_w2, const float* __restrict__ a_b2,
    float* __restrict__ out)
{
    __shared__ float cf[256], hbuf[128], red[4], sc[2], adv[10];
    int t = threadIdx.x;
    float mean, inv;
    float te = task_b[t];
#pragma unroll
    for (int k = 0; k < 4; ++k) te += tf[k] * task_w[k * 128 + t];
    ln_stats128(te, red, mean, inv);
    te = lrelu((te - mean) * inv * task_g[t] + task_be[t], 0.01f);
    cf[t] = gf[t]; cf[128 + t] = te;
    __syncthreads();
    float v = v_b1[t];
    for (int k = 0; k < 256; ++k) v += cf[k] * v_w1[k * 128 + t];
    ln_stats128(v, red, mean, inv);
    v = lrelu((v - mean) * inv * v_g[t] + v_be[t], 0.01f);
    float pv = v * v_w2[t];
#pragma unroll
    for (int m = 32; m >= 1; m >>= 1) pv += __shfl_xor(pv, m);
    __syncthreads();
    if ((t & 63) == 0) red[t >> 6] = pv;
    __syncthreads();
    if (t == 0) sc[0] = red[0] + red[1] + v_b2[0];
    float a = a_b1[t];
    for (int k = 0; k < 256; ++k) a += cf[k] * a_w1[k * 128 + t];
    ln_stats128(a, red, mean, inv);
    a = lrelu((a - mean) * inv * a_g[t] + a_be[t], 0.01f);
    hbuf[t] = a;
    __syncthreads();
    if (t < 10) {
        float s = a_b2[t];
        for (int c = 0; c < 128; ++c) s += hbuf[c] * a_w2[c * 10 + t];
        adv[t] = s;
    }
    __syncthreads();
    if (t == 0) {
        float m10 = 0.f;
        for (int o = 0; o < 10; ++o) m10 += adv[o];
        sc[1] = m10 * 0.1f;
    }
    __syncthreads();
    if (t < 10) out[t] = sc[0] + adv[t] - sc[1];
}

extern "C" void kernel_launch(void* const* d_in, const int* in_sizes, int n_in,
                              void* d_out, int out_size, void* d_ws, size_t ws_size,
                              hipStream_t stream)
{
    const float* x        = (const float*)d_in[0];
    const int*   ei       = (const int*)d_in[1];
    const float* ea       = (const float*)d_in[2];
    const float* tf       = (const float*)d_in[3];
    const float* emb_w    = (const float*)d_in[4];
    const float* emb_b    = (const float*)d_in[5];
    const float* emb_g    = (const float*)d_in[6];
    const float* emb_beta = (const float*)d_in[7];
    const float* gat_w    = (const float*)d_in[8];
    const float* gat_as   = (const float*)d_in[9];
    const float* gat_ad   = (const float*)d_in[10];
    const float* gat_bias = (const float*)d_in[11];
    const float* ec_w1    = (const float*)d_in[12];
    const float* ec_b1    = (const float*)d_in[13];
    const float* ec_g1    = (const float*)d_in[14];
    const float* ec_be1   = (const float*)d_in[15];
    const float* ec_w2    = (const float*)d_in[16];
    const float* ec_b2    = (const float*)d_in[17];
    const float* ec_g2    = (const float*)d_in[18];
    const float* ec_be2   = (const float*)d_in[19];
    const float* norm_g   = (const float*)d_in[20];
    const float* norm_b   = (const float*)d_in[21];
    const float* task_w   = (const float*)d_in[22];
    const float* task_b   = (const float*)d_in[23];
    const float* task_g   = (const float*)d_in[24];
    const float* task_be  = (const float*)d_in[25];
    const float* pa_w1    = (const float*)d_in[26];
    const float* pa_b1    = (const float*)d_in[27];
    const float* pa_w2    = (const float*)d_in[28];
    const float* pa_b2    = (const float*)d_in[29];
    const float* v_w1     = (const float*)d_in[30];
    const float* v_b1     = (const float*)d_in[31];
    const float* v_g      = (const float*)d_in[32];
    const float* v_be     = (const float*)d_in[33];
    const float* v_w2     = (const float*)d_in[34];
    const float* v_b2     = (const float*)d_in[35];
    const float* a_w1     = (const float*)d_in[36];
    const float* a_b1     = (const float*)d_in[37];
    const float* a_g      = (const float*)d_in[38];
    const float* a_be     = (const float*)d_in[39];
    const float* a_w2     = (const float*)d_in[40];
    const float* a_b2     = (const float*)d_in[41];

    const int n = in_sizes[0] / 128;   // 25000
    const int e = in_sizes[2];         // 400000
    const int* src = ei;
    const int* dst = ei + e;

    float* ws = (float*)d_ws;
    uint4* wf = (uint4*)ws;                  // 12 * 2048 uint4 = 384KB
    float* base = ws + 98304;
    const size_t NR = (size_t)n * 128;
    float* h    = base;
    float* x0   = base + NR;
    float* ht   = base + 2 * NR;
    float* A    = base + 3 * NR;
    float* B    = base + 4 * NR;
    float* xs   = base + 5 * NR;
    float* a_s  = base + 6 * NR;
    float* a_d  = a_s + (size_t)n * 2;
    float* den  = a_d + (size_t)n * 2;
    float* selfe = den + (size_t)n * 2;
    float* rsA  = selfe + (size_t)n * 2;
    float* rsB  = rsA + n;
    float* score = rsB + n;
    float* stats = score + n;
    float* gf    = stats + 2;
    int*   cnt    = (int*)(gf + 128);
    int*   starts = cnt + n;
    int*   s_src  = starts + (n + 1);
    int*   s_dst  = s_src + e;
    float* s_ea   = (float*)(s_dst + e);

    const int ngb = (n + GROWS - 1) / GROWS;
    const int ng64 = (n + 63) / 64;
    const int ng8 = (n + 7) / 8;

    // ---- one-time: counting-sort edges by dst + weight pre-pack ----
    hipMemsetAsync(cnt, 0, (size_t)n * sizeof(int), stream);
    k_hist<<<(e + 255) / 256, 256, 0, stream>>>(dst, cnt, e);
    k_scan<<<1, 1024, 0, stream>>>(cnt, starts, n);
    hipMemcpyAsync(cnt, starts, (size_t)n * sizeof(int), hipMemcpyDeviceToDevice, stream);
    k_scatter<<<(e + 255) / 256, 256, 0, stream>>>(src, dst, ea, cnt, s_src, s_dst, s_ea, e);
    k_prep<<<96, 256, 0, stream>>>(gat_w, ec_w1, ec_w2, wf);

    // embedding: h = lrelu(LN(x @ emb_w + emb_b)), x0 = h
    k_node_gemm<<<ngb, 256, 0, stream>>>(x, emb_w, emb_b, emb_g, emb_beta, h, x0, n, 1, 0.01f);

    for (int i = 0; i < LL; ++i) {
        k_gemm3<<<ng64, 256, 0, stream>>>(h, wf, i, 3 + 2 * i, 4 + 2 * i,
                                          ec_b1 + i * 128, ht, A, B, n);
        k_gat_scores<<<(n * 2 + 255) / 256, 256, 0, stream>>>(ht, gat_as + i * 128, gat_ad + i * 128,
                                                              a_s, a_d, den, selfe, n);
        k_rowsums<<<ng8, 512, 0, stream>>>(A, B, rsA, rsB, n);
        k_edge_denom2<<<((e + 7) / 8 + 255) / 256, 256, 0, stream>>>(s_src, s_dst, a_s, a_d, den, e);
        k_xsum_init<<<(n * 128 + 255) / 256, 256, 0, stream>>>(ht, selfe, den,
                                                               gat_bias + i * 128, xs, n);
        k_edge_main<<<(e + EB - 1) / EB, 512, 0, stream>>>(A, B, ht, s_src, s_dst, s_ea,
                                                           a_s, a_d, den,
                                                           wf + (size_t)(9 + i) * 2048,
                                                           rsA, rsB,
                                                           ec_g1 + i * 128, ec_be1 + i * 128,
                                                           ec_b2 + i * 128, ec_g2 + i * 128, ec_be2 + i * 128,
                                                           xs, e);
        k_norm8<<<ng8, 512, 0, stream>>>(xs, norm_g + i * 128, norm_b + i * 128, x0, h, n, i);
    }

    k_pool_score<<<(n + 3) / 4, 256, 0, stream>>>(h, pa_w1, pa_b1, pa_w2, pa_b2, score, n);
    k_softmax_reduce<<<1, 256, 0, stream>>>(score, stats, gf, n);
    k_gf<<<200, 128, 0, stream>>>(h, score, stats, gf, n);
    k_head<<<1, 128, 0, stream>>>(gf, tf, task_w, task_b, task_g, task_be,
                                  v_w1, v_b1, v_g, v_be, v_w2, v_b2,
                                  a_w1, a_b1, a_g, a_be, a_w2, a_b2,
                                  (float*)d_out);
}

// Round 5
// 803.460 us; speedup vs baseline: 2.1702x; 1.0347x over previous
//
#include <hip/hip_runtime.h>
#include <math.h>

#define NN 25000
#define EE 400000
#define LL 3
#define LNEPS 1e-5f
#define EB 64

typedef __attribute__((ext_vector_type(8))) short short8;
typedef __attribute__((ext_vector_type(16))) float f32x16;

__device__ __forceinline__ float lrelu(float x, float s) { return fmaxf(x, x * s); }

__device__ __forceinline__ unsigned int pack_bf2(float lo, float hi) {
    unsigned int ul = __float_as_uint(lo), uh = __float_as_uint(hi);
    ul = (ul + 0x7FFFu + ((ul >> 16) & 1u)) >> 16;
    uh = (uh + 0x7FFFu + ((uh >> 16) & 1u)) >> 16;
    return (uh << 16) | (ul & 0xFFFFu);
}

// 128-thread block LN stats (2 waves)
__device__ __forceinline__ void ln_stats128(float v, float* red, float& mean, float& inv) {
    float sm = v, sq = v * v;
#pragma unroll
    for (int m = 32; m >= 1; m >>= 1) { sm += __shfl_xor(sm, m); sq += __shfl_xor(sq, m); }
    __syncthreads();
    if ((threadIdx.x & 63) == 0) { red[(threadIdx.x >> 6) * 2] = sm; red[(threadIdx.x >> 6) * 2 + 1] = sq; }
    __syncthreads();
    sm = red[0] + red[2]; sq = red[1] + red[3];
    mean = sm * (1.f / 128.f);
    float var = sq * (1.f / 128.f) - mean * mean;
    inv = rsqrtf(var + LNEPS);
}

// ================= edge sorting (counting sort by dst) =================
__global__ void k_hist(const int* __restrict__ dst, int* __restrict__ cnt, int ne)
{
    int i = blockIdx.x * 256 + threadIdx.x;
    if (i < ne) atomicAdd(&cnt[dst[i]], 1);
}

__global__ __launch_bounds__(1024) void k_scan(const int* __restrict__ cnt,
                                               int* __restrict__ starts, int n)
{
    __shared__ int tot[1024];
    int t = threadIdx.x;
    const int PER = (n + 1023) >> 10;
    int i0 = t * PER;
    int s = 0;
    for (int k = 0; k < PER; ++k) { int i = i0 + k; s += (i < n) ? cnt[i] : 0; }
    tot[t] = s;
    __syncthreads();
    for (int off = 1; off < 1024; off <<= 1) {
        int x = (t >= off) ? tot[t - off] : 0;
        __syncthreads();
        tot[t] += x;
        __syncthreads();
    }
    int run = (t > 0) ? tot[t - 1] : 0;
    for (int k = 0; k < PER; ++k) {
        int i = i0 + k;
        if (i < n) { starts[i] = run; run += cnt[i]; }
    }
    if (t == 1023) starts[n] = tot[1023];
}

__global__ void k_scatter(const int* __restrict__ src, const int* __restrict__ dst,
                          const float* __restrict__ ea, int* __restrict__ cursor,
                          int* __restrict__ s_src, int* __restrict__ s_dst,
                          float* __restrict__ s_ea, int ne)
{
    int i = blockIdx.x * 256 + threadIdx.x;
    if (i >= ne) return;
    int d = dst[i];
    int pos = atomicAdd(&cursor[d], 1);
    s_src[pos] = src[i];
    s_dst[pos] = d;
    s_ea[pos] = ea[i];
}

// ================= weight pre-pack: fp32 [128x128] -> bf16 B-fragment order ====
// mat m: 0..2 gat_w[i]; 3..8 ec_w1 layer (m-3)>>1 half (m-3)&1; 9..11 ec_w2[i]; 12 emb_w
__global__ void k_prep(const float* __restrict__ gat_w, const float* __restrict__ ec_w1,
                       const float* __restrict__ ec_w2, const float* __restrict__ emb_w,
                       uint4* __restrict__ wf)
{
    int g = blockIdx.x * 256 + threadIdx.x;   // < 13*2048
    int m = g >> 11, f = g & 2047;
    const float* srcm;
    if (m < 3) srcm = gat_w + (size_t)m * 16384;
    else if (m < 9) { int t2 = m - 3; srcm = ec_w1 + (size_t)(t2 >> 1) * 32768 + (size_t)(t2 & 1) * 16384; }
    else if (m < 12) srcm = ec_w2 + (size_t)(m - 9) * 16384;
    else srcm = emb_w;
    int l = f & 63, ks = (f >> 6) & 7, nb = f >> 9;
    int k0 = ks * 16 + (l >> 5) * 8, col = nb * 32 + (l & 31);
    const float* wp = srcm + (size_t)k0 * 128 + col;
    uint4 r;
    r.x = pack_bf2(wp[0],   wp[128]);
    r.y = pack_bf2(wp[256], wp[384]);
    r.z = pack_bf2(wp[512], wp[640]);
    r.w = pack_bf2(wp[768], wp[896]);
    wf[g] = r;
}

// ---- MFMA embedding: h = x0 = lrelu(LN(x @ emb_w + emb_b)) ----
__global__ __launch_bounds__(256) void k_emb(
    const float* __restrict__ in, const uint4* __restrict__ wfm,
    const float* __restrict__ bias, const float* __restrict__ g,
    const float* __restrict__ be, float* __restrict__ h,
    float* __restrict__ x0, int nrows)
{
    __shared__ __align__(16) unsigned int sA[64 * 64];
    __shared__ __align__(16) unsigned int sW[2048 * 4];   // 32KB, reused as sU
    float* sU = (float*)sW;
    const int tid = threadIdx.x;
    const int r0 = blockIdx.x * 64;
    {
        int row = tid >> 2, q = tid & 3;
        const float* srcp = in + (size_t)(r0 + row) * 128 + q * 32;
        bool ok = (r0 + row) < nrows;
#pragma unroll
        for (int i = 0; i < 8; ++i) {
            float4 v = ok ? *(const float4*)&srcp[i * 4] : make_float4(0.f, 0.f, 0.f, 0.f);
            int cu = (q * 16 + i * 2) ^ ((row & 15) << 2);
            *(uint2*)&sA[row * 64 + cu] = make_uint2(pack_bf2(v.x, v.y), pack_bf2(v.z, v.w));
        }
    }
    {
        uint4* sW4 = (uint4*)sW;
#pragma unroll
        for (int i = 0; i < 8; ++i) sW4[tid + 256 * i] = wfm[tid + 256 * i];
    }
    __syncthreads();
    const int w = tid >> 6, l = tid & 63;
    const int m0 = (w >> 1) * 32, nhalf = (w & 1);
    f32x16 acc0 = {}, acc1 = {};
#pragma unroll
    for (int ks = 0; ks < 8; ++ks) {
        int rw = m0 + (l & 31);
        int cu = (ks * 8 + (l >> 5) * 4) ^ ((rw & 15) << 2);
        short8 a = *(const short8*)&sA[rw * 64 + cu];
        short8 b0 = *(const short8*)&sW[((nhalf * 16 + ks) * 64 + l) * 4];
        short8 b1 = *(const short8*)&sW[(((nhalf * 2 + 1) * 8 + ks) * 64 + l) * 4];
        acc0 = __builtin_amdgcn_mfma_f32_32x32x16_bf16(a, b0, acc0, 0, 0, 0);
        acc1 = __builtin_amdgcn_mfma_f32_32x32x16_bf16(a, b1, acc1, 0, 0, 0);
    }
    __syncthreads();   // all waves done reading sW
    {
        int colbase = nhalf * 64 + (l & 31);
        float bb0 = bias[colbase], bb1 = bias[colbase + 32];
#pragma unroll
        for (int r = 0; r < 16; ++r) {
            int rw = m0 + (r & 3) + 8 * (r >> 2) + 4 * (l >> 5);
            sU[rw * 128 + colbase]      = acc0[r] + bb0;
            sU[rw * 128 + colbase + 32] = acc1[r] + bb1;
        }
    }
    __syncthreads();
    // LN epilogue: 4 waves x 16 rows
    float2 gv = *(const float2*)&g[l * 2];
    float2 bv = *(const float2*)&be[l * 2];
    for (int it = 0; it < 16; ++it) {
        int rw = w * 16 + it;
        int grow = r0 + rw;
        if (grow >= nrows) break;
        float2 v = *(const float2*)&sU[rw * 128 + l * 2];
        float sm = v.x + v.y, sq = v.x * v.x + v.y * v.y;
#pragma unroll
        for (int m = 32; m >= 1; m >>= 1) { sm += __shfl_xor(sm, m); sq += __shfl_xor(sq, m); }
        float mean = sm * (1.f / 128.f);
        float var = sq * (1.f / 128.f) - mean * mean;
        float inv = rsqrtf(var + LNEPS);
        float o0 = lrelu((v.x - mean) * inv * gv.x + bv.x, 0.01f);
        float o1 = lrelu((v.y - mean) * inv * gv.y + bv.y, 0.01f);
        unsigned off = (unsigned)grow * 128u + (unsigned)(l * 2);
        *(float2*)&h[off]  = make_float2(o0, o1);
        *(float2*)&x0[off] = make_float2(o0, o1);
    }
}

// ---- MFMA 3-in-1 node GEMM: {ht, A'(+b1), B} = h @ {Wht, WA, WB} ----
__global__ __launch_bounds__(256) void k_gemm3(
    const float* __restrict__ in, const uint4* __restrict__ wf,
    int mht, int mA, int mB, const float* __restrict__ bA,
    float* __restrict__ o0, float* __restrict__ o1, float* __restrict__ o2,
    int nrows)
{
    __shared__ __align__(16) unsigned int sA[64 * 64];     // 16KB bf16 tile, XOR-swizzled
    __shared__ __align__(16) unsigned int sW[2048 * 4];    // 32KB B-fragments
    const int tid = threadIdx.x;
    const int r0 = blockIdx.x * 64;
    {
        int row = tid >> 2, q = tid & 3;
        const float* srcp = in + (size_t)(r0 + row) * 128 + q * 32;
        bool ok = (r0 + row) < nrows;
#pragma unroll
        for (int i = 0; i < 8; ++i) {
            float4 v = ok ? *(const float4*)&srcp[i * 4] : make_float4(0.f, 0.f, 0.f, 0.f);
            unsigned int p0 = pack_bf2(v.x, v.y), p1 = pack_bf2(v.z, v.w);
            int cu = (q * 16 + i * 2) ^ ((row & 15) << 2);
            *(uint2*)&sA[row * 64 + cu] = make_uint2(p0, p1);
        }
    }
    __syncthreads();
    const int w = tid >> 6, l = tid & 63;
    const int m0 = (w >> 1) * 32, nhalf = (w & 1);
    short8 af[8];
#pragma unroll
    for (int ks = 0; ks < 8; ++ks) {
        int row = m0 + (l & 31);
        int cu = (ks * 8 + (l >> 5) * 4) ^ ((row & 15) << 2);
        af[ks] = *(const short8*)&sA[row * 64 + cu];
    }
    auto do_mat = [&](int mat, float* out, const float* bp) {
        __syncthreads();
        {
            const uint4* wsrc = wf + (size_t)mat * 2048;
            uint4* sW4 = (uint4*)sW;
#pragma unroll
            for (int i = 0; i < 8; ++i) sW4[tid + 256 * i] = wsrc[tid + 256 * i];
        }
        __syncthreads();
        f32x16 acc0 = {}, acc1 = {};
        const int nb0 = nhalf * 2;
#pragma unroll
        for (int ks = 0; ks < 8; ++ks) {
            short8 b0 = *(const short8*)&sW[((nb0 * 8 + ks) * 64 + l) * 4];
            short8 b1v = *(const short8*)&sW[(((nb0 + 1) * 8 + ks) * 64 + l) * 4];
            acc0 = __builtin_amdgcn_mfma_f32_32x32x16_bf16(af[ks], b0, acc0, 0, 0, 0);
            acc1 = __builtin_amdgcn_mfma_f32_32x32x16_bf16(af[ks], b1v, acc1, 0, 0, 0);
        }
        int colbase = nhalf * 64 + (l & 31);
        float badd0 = bp ? bp[colbase] : 0.f;
        float badd1 = bp ? bp[colbase + 32] : 0.f;
#pragma unroll
        for (int r = 0; r < 16; ++r) {
            int row = r0 + m0 + (r & 3) + 8 * (r >> 2) + 4 * (l >> 5);
            if (row < nrows) {
                unsigned off = (unsigned)row * 128u + (unsigned)colbase;
                out[off]      = acc0[r] + badd0;
                out[off + 32] = acc1[r] + badd1;
            }
        }
    };
    do_mat(mht, o0, nullptr);
    do_mat(mA, o1, bA);
    do_mat(mB, o2, nullptr);
}

// ---- merged per-node pass: GAT scores + selfe/denom init + row sums of A',B ----
__global__ __launch_bounds__(512) void k_node_scores(
    const float* __restrict__ ht, const float* __restrict__ A, const float* __restrict__ B,
    const float* __restrict__ as_, const float* __restrict__ ad_,
    float* __restrict__ a_s, float* __restrict__ a_d,
    float* __restrict__ denom, float* __restrict__ selfe,
    float* __restrict__ rsA, float* __restrict__ rsB, int n)
{
    int wv = threadIdx.x >> 6, ln = threadIdx.x & 63;
    int node = blockIdx.x * 8 + wv;
    if (node >= n) return;
    unsigned off = (unsigned)node * 128u + (unsigned)(ln * 2);
    float2 hv = *(const float2*)&ht[off];
    float2 av = *(const float2*)&A[off];
    float2 bv = *(const float2*)&B[off];
    float2 wsv = *(const float2*)&as_[ln * 2];
    float2 wdv = *(const float2*)&ad_[ln * 2];
    float ss = hv.x * wsv.x + hv.y * wsv.y;
    float sd = hv.x * wdv.x + hv.y * wdv.y;
    float sa = av.x + av.y, sb = bv.x + bv.y;
#pragma unroll
    for (int m = 16; m >= 1; m >>= 1) {
        ss += __shfl_xor(ss, m); sd += __shfl_xor(sd, m);
        sa += __shfl_xor(sa, m); sb += __shfl_xor(sb, m);
    }
    float sa2 = sa + __shfl_xor(sa, 32);
    float sb2 = sb + __shfl_xor(sb, 32);
    if ((ln & 31) == 0) {
        int hd = ln >> 5;
        a_s[node * 2 + hd] = ss;
        a_d[node * 2 + hd] = sd;
        float ev = expf(lrelu(ss + sd, 0.2f));
        denom[node * 2 + hd] = ev;
        selfe[node * 2 + hd] = ev;
        if (hd == 0) { rsA[node] = sa2; rsB[node] = sb2; }
    }
}

// ---- accumulate exp(e) per dst over sorted edges, run-merged ----
__global__ void k_edge_denom2(const int* __restrict__ s_src, const int* __restrict__ s_dst,
                              const float* __restrict__ a_s, const float* __restrict__ a_d,
                              float* __restrict__ denom, int ne)
{
    int base = (blockIdx.x * 256 + threadIdx.x) * 8;
    if (base >= ne) return;
    int curd = -1;
    float acc0 = 0.f, acc1 = 0.f;
    for (int k = 0; k < 8; ++k) {
        int e = base + k;
        if (e >= ne) break;
        int s = s_src[e], d = s_dst[e];
        float v0 = expf(lrelu(a_s[(unsigned)(s * 2)]     + a_d[(unsigned)(d * 2)],     0.2f));
        float v1 = expf(lrelu(a_s[(unsigned)(s * 2 + 1)] + a_d[(unsigned)(d * 2 + 1)], 0.2f));
        if (d != curd) {
            if (curd >= 0) { atomicAdd(&denom[curd * 2], acc0); atomicAdd(&denom[curd * 2 + 1], acc1); }
            curd = d; acc0 = v0; acc1 = v1;
        } else { acc0 += v0; acc1 += v1; }
    }
    if (curd >= 0) { atomicAdd(&denom[curd * 2], acc0); atomicAdd(&denom[curd * 2 + 1], acc1); }
}

// ---- xsum = gat_bias + self-loop GAT contribution ----
__global__ void k_xsum_init(const float* __restrict__ ht, const float* __restrict__ selfe,
                            const float* __restrict__ denom,
                            const float* __restrict__ gbias, float* __restrict__ xsum, int n)
{
    unsigned idx = blockIdx.x * blockDim.x + threadIdx.x;
    if (idx >= (unsigned)n * 128u) return;
    unsigned node = idx >> 7, c = idx & 127, hd = c >> 6;
    float alpha = selfe[node * 2 + hd] / denom[node * 2 + hd];
    xsum[idx] = gbias[c] + ht[idx] * alpha;
}

// ---- fused edge kernel (dst-sorted): EdgeConv MLP (MFMA) + GAT, run-merged scatter ----
__global__ __launch_bounds__(512) void k_edge_main(
    const float* __restrict__ Abuf, const float* __restrict__ Bbuf,
    const float* __restrict__ ht,
    const int* __restrict__ s_src, const int* __restrict__ s_dst,
    const float* __restrict__ s_ea,
    const float* __restrict__ a_s, const float* __restrict__ a_d,
    const float* __restrict__ denom,
    const uint4* __restrict__ w2f,
    const float* __restrict__ rsA, const float* __restrict__ rsB,
    const float* __restrict__ g1, const float* __restrict__ be1,
    const float* __restrict__ b2, const float* __restrict__ g2, const float* __restrict__ be2,
    float* __restrict__ xsum, int ne)
{
    // sWB: W2 bf16 B-fragments (32KB); reused after phase 2 as fp32 sU[64][128].
    __shared__ __align__(16) unsigned int sWB[2048 * 4];
    __shared__ __align__(16) unsigned int sT32[EB * 64];   // t tile bf16 pairs, XOR-swizzled
    __shared__ int   sS[EB], sD[EB];
    __shared__ float sEA[EB], sM[EB];
    __shared__ float sAl[EB * 2];
    __shared__ float sG1[128], sE1[128], sB2[128], sG2[128], sE2[128];
    float* sU = (float*)sWB;

    const int tid = threadIdx.x;
    {   // stage W2 fragments: pure copy (pre-packed by k_prep)
        uint4* sWB4 = (uint4*)sWB;
#pragma unroll
        for (int i = 0; i < 4; ++i) { int f = tid + 512 * i; sWB4[f] = w2f[f]; }
    }
    if (tid < 128) {
        sG1[tid] = g1[tid]; sE1[tid] = be1[tid];
        sB2[tid] = b2[tid]; sG2[tid] = g2[tid]; sE2[tid] = be2[tid];
    }
    const int e0 = blockIdx.x * EB;
    const int nev = (ne - e0 < EB) ? (ne - e0) : EB;
    if (tid < EB) {
        if (tid < nev) {
            int s = s_src[e0 + tid], d = s_dst[e0 + tid];
            sS[tid] = s; sD[tid] = d; sEA[tid] = s_ea[e0 + tid];
            sM[tid] = (rsA[s] + rsB[d]) * (1.f / 128.f);
        } else { sS[tid] = 0; sD[tid] = -1; sEA[tid] = 0.f; sM[tid] = 0.f; }
    }
    if (tid < 2 * EB) {
        int le = tid >> 1, hd = tid & 1;
        float al = 0.f;
        if (le < nev) {
            int e = e0 + le;
            int s = s_src[e], d = s_dst[e];
            float ev = lrelu(a_s[(unsigned)(s * 2 + hd)] + a_d[(unsigned)(d * 2 + hd)], 0.2f);
            al = expf(ev) / denom[(unsigned)(d * 2 + hd)];
        }
        sAl[le * 2 + hd] = al;
    }
    __syncthreads();

    // phase 1: t = lrelu(LN(A'[src]+B[dst]), 0.2) -> bf16 LDS (mean precomputed)
    const int wv = tid >> 6, ln = tid & 63;
    const unsigned ln2 = (unsigned)(ln * 2);
    {
        const float g1a = sG1[ln * 2], g1b = sG1[ln * 2 + 1];
        const float e1a = sE1[ln * 2], e1b = sE1[ln * 2 + 1];
        for (int j = 0; j < 8; ++j) {
            int e = wv * 8 + j;
            if (e < nev) {
                unsigned s = (unsigned)sS[e], d = (unsigned)sD[e];
                float mean = sM[e];
                float2 av = *(const float2*)&Abuf[s * 128u + ln2];
                float2 bv = *(const float2*)&Bbuf[d * 128u + ln2];
                float v0 = av.x + bv.x - mean;
                float v1 = av.y + bv.y - mean;
                float sq = v0 * v0 + v1 * v1;
#pragma unroll
                for (int m = 32; m >= 1; m >>= 1) sq += __shfl_xor(sq, m);
                float inv = rsqrtf(sq * (1.f / 128.f) + LNEPS);
                float t0 = lrelu(v0 * inv * g1a + e1a, 0.2f);
                float t1 = lrelu(v1 * inv * g1b + e1b, 0.2f);
                sT32[e * 64 + (ln ^ ((e & 15) << 2))] = pack_bf2(t0, t1);
            }
        }
    }
    __syncthreads();

    // phase 2: u = t @ W2 via MFMA. 8 waves, each one 32x32 output tile.
    {
        const int w = wv, l = ln;
        const int m0 = (w >> 2) * 32, n0 = (w & 3) * 32;
        f32x16 acc = {};
#pragma unroll
        for (int ks = 0; ks < 8; ++ks) {
            int row = m0 + (l & 31);
            int colu = (ks * 8 + (l >> 5) * 4) ^ ((row & 15) << 2);
            short8 a = *(const short8*)&sT32[row * 64 + colu];
            short8 b = *(const short8*)&sWB[((((w & 3) * 8 + ks) * 64 + l)) * 4];
            acc = __builtin_amdgcn_mfma_f32_32x32x16_bf16(a, b, acc, 0, 0, 0);
        }
        __syncthreads();   // all waves done reading sWB before overwriting as sU
        float b2c = sB2[n0 + (l & 31)];
#pragma unroll
        for (int r = 0; r < 16; ++r) {
            int row = m0 + (r & 3) + 8 * (r >> 2) + 4 * (l >> 5);
            sU[row * 128 + n0 + (l & 31)] = acc[r] + b2c;
        }
    }
    __syncthreads();

    // phase 3: LN(u)+lrelu, *edge_attr, + GAT ht[src]*alpha; run-merged atomic scatter
    {
        const float g2a = sG2[ln * 2], g2b = sG2[ln * 2 + 1];
        const float e2a = sE2[ln * 2], e2b = sE2[ln * 2 + 1];
        int curd = -1;
        float acc0 = 0.f, acc1 = 0.f;
        for (int j = 0; j < 8; ++j) {
            int e = wv * 8 + j;
            if (e >= nev) break;
            unsigned s = (unsigned)sS[e];
            int d = sD[e];
            float2 uv = *(const float2*)&sU[e * 128 + ln * 2];
            float u0 = uv.x, u1 = uv.y;
            float sm = u0 + u1, sq = u0 * u0 + u1 * u1;
#pragma unroll
            for (int m = 32; m >= 1; m >>= 1) { sm += __shfl_xor(sm, m); sq += __shfl_xor(sq, m); }
            float mean = sm * (1.f / 128.f);
            float var = sq * (1.f / 128.f) - mean * mean;
            float inv = rsqrtf(var + LNEPS);
            float eav = sEA[e];
            float v0 = lrelu((u0 - mean) * inv * g2a + e2a, 0.2f) * eav;
            float v1 = lrelu((u1 - mean) * inv * g2b + e2b, 0.2f) * eav;
            float al = sAl[e * 2 + (ln >> 5)];
            float2 hv = *(const float2*)&ht[s * 128u + ln2];
            v0 += hv.x * al;
            v1 += hv.y * al;
            if (d != curd) {
                if (curd >= 0) {
                    atomicAdd(&xsum[(unsigned)curd * 128u + ln2], acc0);
                    atomicAdd(&xsum[(unsigned)curd * 128u + ln2 + 1], acc1);
                }
                curd = d; acc0 = v0; acc1 = v1;
            } else { acc0 += v0; acc1 += v1; }
        }
        if (curd >= 0) {
            atomicAdd(&xsum[(unsigned)curd * 128u + ln2], acc0);
            atomicAdd(&xsum[(unsigned)curd * 128u + ln2 + 1], acc1);
        }
    }
}

// ---- h = lrelu(LN(xsum)) (+ x0 residual), wave-per-node ----
__global__ __launch_bounds__(512) void k_norm8(const float* __restrict__ xsum,
                                               const float* __restrict__ g,
                                               const float* __restrict__ b,
                                               float* __restrict__ x0,
                                               float* __restrict__ h, int n, int layer)
{
    int wv = threadIdx.x >> 6, ln = threadIdx.x & 63;
    int node = blockIdx.x * 8 + wv;
    if (node >= n) return;
    unsigned off = (unsigned)node * 128u + (unsigned)(ln * 2);
    float2 v = *(const float2*)&xsum[off];
    float sm = v.x + v.y, sq = v.x * v.x + v.y * v.y;
#pragma unroll
    for (int m = 32; m >= 1; m >>= 1) { sm += __shfl_xor(sm, m); sq += __shfl_xor(sq, m); }
    float mean = sm * (1.f / 128.f);
    float var = sq * (1.f / 128.f) - mean * mean;
    float inv = rsqrtf(var + LNEPS);
    float2 gv = *(const float2*)&g[ln * 2];
    float2 bv = *(const float2*)&b[ln * 2];
    float val0 = lrelu((v.x - mean) * inv * gv.x + bv.x, 0.01f);
    float val1 = lrelu((v.y - mean) * inv * gv.y + bv.y, 0.01f);
    if (layer > 0) {
        float2 x0v = *(const float2*)&x0[off];
        val0 += x0v.x; val1 += x0v.y;
        *(float2*)&x0[off] = make_float2(val0, val1);
    }
    *(float2*)&h[off] = make_float2(val0, val1);
}

// ---- pooling attention scores (one node per wave) ----
__global__ __launch_bounds__(256) void k_pool_score(const float* __restrict__ h,
    const float* __restrict__ w1, const float* __restrict__ b1,
    const float* __restrict__ w2, const float* __restrict__ b2,
    float* __restrict__ score, int n)
{
    int wv = threadIdx.x >> 6, ln = threadIdx.x & 63;
    int node = blockIdx.x * 4 + wv;
    if (node >= n) return;
    float acc = b1[ln];
    const float* hr = h + (size_t)node * 128;
    for (int k = 0; k < 128; ++k) acc += hr[k] * w1[k * 64 + ln];
    acc = lrelu(acc, 0.01f) * w2[ln];
#pragma unroll
    for (int m = 32; m >= 1; m >>= 1) acc += __shfl_xor(acc, m);
    if (ln == 0) score[node] = acc + b2[0];
}

// ---- softmax stats (single block) + zero gf ----
__global__ __launch_bounds__(256) void k_softmax_reduce(const float* __restrict__ score,
                                                        float* __restrict__ stats,
                                                        float* __restrict__ gf, int n)
{
    __shared__ float red[8];
    int t = threadIdx.x;
    float mx = -1e30f;
    for (int i = t; i < n; i += 256) mx = fmaxf(mx, score[i]);
#pragma unroll
    for (int m = 32; m >= 1; m >>= 1) mx = fmaxf(mx, __shfl_xor(mx, m));
    if ((t & 63) == 0) red[t >> 6] = mx;
    __syncthreads();
    mx = fmaxf(fmaxf(red[0], red[1]), fmaxf(red[2], red[3]));
    float s = 0.f;
    for (int i = t; i < n; i += 256) s += expf(score[i] - mx);
#pragma unroll
    for (int m = 32; m >= 1; m >>= 1) s += __shfl_xor(s, m);
    if ((t & 63) == 0) red[4 + (t >> 6)] = s;
    __syncthreads();
    s = red[4] + red[5] + red[6] + red[7];
    if (t == 0) { stats[0] = mx; stats[1] = s; }
    if (t < 128) gf[t] = 0.f;
}

// ---- gf = sum_n softmax(score)[n] * h[n,:] ----
__global__ __launch_bounds__(128) void k_gf(const float* __restrict__ h,
                                            const float* __restrict__ score,
                                            const float* __restrict__ stats,
                                            float* __restrict__ gf, int n)
{
    int c = threadIdx.x;
    float mx = stats[0], invZ = 1.f / stats[1];
    int per = (n + gridDim.x - 1) / gridDim.x;
    int n0 = blockIdx.x * per;
    int n1 = n0 + per; if (n1 > n) n1 = n;
    float acc = 0.f;
    for (int i = n0; i < n1; ++i)
        acc += expf(score[i] - mx) * invZ * h[(size_t)i * 128 + c];
    atomicAdd(&gf[c], acc);
}

// ---- final head (single 128-thread block) ----
__global__ __launch_bounds__(128) void k_head(
    const float* __restrict__ gf, const float* __restrict__ tf,
    const float* __restrict__ task_w, const float* __restrict__ task_b,
    const float* __restrict__ task_g, const float* __restrict__ task_be,
    const float* __restrict__ v_w1, const float* __restrict__ v_b1,
    const float* __restrict__ v_g, const float* __restrict__ v_be,
    const float* __restrict__ v_w2, const float* __restrict__ v_b2,
    const float* __restrict__ a_w1, const float* __restrict__ a_b1,
    const float* __restrict__ a_g, const float* __restrict__ a_be,
    const float* __restrict__ a_w2, const float* __restrict__ a_b2,
    float* __restrict__ out)
{
    __shared__ float cf[256], hbuf[128], red[4], sc[2], adv[10];
    int t = threadIdx.x;
    float mean, inv;
    float te = task_b[t];
#pragma unroll
    for (int k = 0; k < 4; ++k) te += tf[k] * task_w[k * 128 + t];
    ln_stats128(te, red, mean, inv);
    te = lrelu((te - mean) * inv * task_g[t] + task_be[t], 0.01f);
    cf[t] = gf[t]; cf[128 + t] = te;
    __syncthreads();
    float v = v_b1[t];
    for (int k = 0; k < 256; ++k) v += cf[k] * v_w1[k * 128 + t];
    ln_stats128(v, red, mean, inv);
    v = lrelu((v - mean) * inv * v_g[t] + v_be[t], 0.01f);
    float pv = v * v_w2[t];
#pragma unroll
    for (int m = 32; m >= 1; m >>= 1) pv += __shfl_xor(pv, m);
    __syncthreads();
    if ((t & 63) == 0) red[t >> 6] = pv;
    __syncthreads();
    if (t == 0) sc[0] = red[0] + red[1] + v_b2[0];
    float a = a_b1[t];
    for (int k = 0; k < 256; ++k) a += cf[k] * a_w1[k * 128 + t];
    ln_stats128(a, red, mean, inv);
    a = lrelu((a - mean) * inv * a_g[t] + a_be[t], 0.01f);
    hbuf[t] = a;
    __syncthreads();
    if (t < 10) {
        float s = a_b2[t];
        for (int c = 0; c < 128; ++c) s += hbuf[c] * a_w2[c * 10 + t];
        adv[t] = s;
    }
    __syncthreads();
    if (t == 0) {
        float m10 = 0.f;
        for (int o = 0; o < 10; ++o) m10 += adv[o];
        sc[1] = m10 * 0.1f;
    }
    __syncthreads();
    if (t < 10) out[t] = sc[0] + adv[t] - sc[1];
}

extern "C" void kernel_launch(void* const* d_in, const int* in_sizes, int n_in,
                              void* d_out, int out_size, void* d_ws, size_t ws_size,
                              hipStream_t stream)
{
    const float* x        = (const float*)d_in[0];
    const int*   ei       = (const int*)d_in[1];
    const float* ea       = (const float*)d_in[2];
    const float* tf       = (const float*)d_in[3];
    const float* emb_w    = (const float*)d_in[4];
    const float* emb_b    = (const float*)d_in[5];
    const float* emb_g    = (const float*)d_in[6];
    const float* emb_beta = (const float*)d_in[7];
    const float* gat_w    = (const float*)d_in[8];
    const float* gat_as   = (const float*)d_in[9];
    const float* gat_ad   = (const float*)d_in[10];
    const float* gat_bias = (const float*)d_in[11];
    const float* ec_w1    = (const float*)d_in[12];
    const float* ec_b1    = (const float*)d_in[13];
    const float* ec_g1    = (const float*)d_in[14];
    const float* ec_be1   = (const float*)d_in[15];
    const float* ec_w2    = (const float*)d_in[16];
    const float* ec_b2    = (const float*)d_in[17];
    const float* ec_g2    = (const float*)d_in[18];
    const float* ec_be2   = (const float*)d_in[19];
    const float* norm_g   = (const float*)d_in[20];
    const float* norm_b   = (const float*)d_in[21];
    const float* task_w   = (const float*)d_in[22];
    const float* task_b   = (const float*)d_in[23];
    const float* task_g   = (const float*)d_in[24];
    const float* task_be  = (const float*)d_in[25];
    const float* pa_w1    = (const float*)d_in[26];
    const float* pa_b1    = (const float*)d_in[27];
    const float* pa_w2    = (const float*)d_in[28];
    const float* pa_b2    = (const float*)d_in[29];
    const float* v_w1     = (const float*)d_in[30];
    const float* v_b1     = (const float*)d_in[31];
    const float* v_g      = (const float*)d_in[32];
    const float* v_be     = (const float*)d_in[33];
    const float* v_w2     = (const float*)d_in[34];
    const float* v_b2     = (const float*)d_in[35];
    const float* a_w1     = (const float*)d_in[36];
    const float* a_b1     = (const float*)d_in[37];
    const float* a_g      = (const float*)d_in[38];
    const float* a_be     = (const float*)d_in[39];
    const float* a_w2     = (const float*)d_in[40];
    const float* a_b2     = (const float*)d_in[41];

    const int n = in_sizes[0] / 128;   // 25000
    const int e = in_sizes[2];         // 400000
    const int* src = ei;
    const int* dst = ei + e;

    float* ws = (float*)d_ws;
    uint4* wf = (uint4*)ws;                  // 13 * 2048 uint4 = 416KB
    float* base = ws + 13 * 2048 * 4;
    const size_t NR = (size_t)n * 128;
    float* h    = base;
    float* x0   = base + NR;
    float* ht   = base + 2 * NR;
    float* A    = base + 3 * NR;
    float* B    = base + 4 * NR;
    float* xs   = base + 5 * NR;
    float* a_s  = base + 6 * NR;
    float* a_d  = a_s + (size_t)n * 2;
    float* den  = a_d + (size_t)n * 2;
    float* selfe = den + (size_t)n * 2;
    float* rsA  = selfe + (size_t)n * 2;
    float* rsB  = rsA + n;
    float* score = rsB + n;
    float* stats = score + n;
    float* gf    = stats + 2;
    int*   cnt    = (int*)(gf + 128);
    int*   starts = cnt + n;
    int*   s_src  = starts + (n + 1);
    int*   s_dst  = s_src + e;
    float* s_ea   = (float*)(s_dst + e);

    const int ng64 = (n + 63) / 64;
    const int ng8 = (n + 7) / 8;

    // ---- one-time: counting-sort edges by dst + weight pre-pack ----
    hipMemsetAsync(cnt, 0, (size_t)n * sizeof(int), stream);
    k_hist<<<(e + 255) / 256, 256, 0, stream>>>(dst, cnt, e);
    k_scan<<<1, 1024, 0, stream>>>(cnt, starts, n);
    hipMemcpyAsync(cnt, starts, (size_t)n * sizeof(int), hipMemcpyDeviceToDevice, stream);
    k_scatter<<<(e + 255) / 256, 256, 0, stream>>>(src, dst, ea, cnt, s_src, s_dst, s_ea, e);
    k_prep<<<104, 256, 0, stream>>>(gat_w, ec_w1, ec_w2, emb_w, wf);

    // embedding: h = x0 = lrelu(LN(x @ emb_w + emb_b))
    k_emb<<<ng64, 256, 0, stream>>>(x, wf + (size_t)12 * 2048, emb_b, emb_g, emb_beta, h, x0, n);

    for (int i = 0; i < LL; ++i) {
        k_gemm3<<<ng64, 256, 0, stream>>>(h, wf, i, 3 + 2 * i, 4 + 2 * i,
                                          ec_b1 + i * 128, ht, A, B, n);
        k_node_scores<<<ng8, 512, 0, stream>>>(ht, A, B, gat_as + i * 128, gat_ad + i * 128,
                                               a_s, a_d, den, selfe, rsA, rsB, n);
        k_edge_denom2<<<((e + 7) / 8 + 255) / 256, 256, 0, stream>>>(s_src, s_dst, a_s, a_d, den, e);
        k_xsum_init<<<(n * 128 + 255) / 256, 256, 0, stream>>>(ht, selfe, den,
                                                               gat_bias + i * 128, xs, n);
        k_edge_main<<<(e + EB - 1) / EB, 512, 0, stream>>>(A, B, ht, s_src, s_dst, s_ea,
                                                           a_s, a_d, den,
                                                           wf + (size_t)(9 + i) * 2048,
                                                           rsA, rsB,
                                                           ec_g1 + i * 128, ec_be1 + i * 128,
                                                           ec_b2 + i * 128, ec_g2 + i * 128, ec_be2 + i * 128,
                                                           xs, e);
        k_norm8<<<ng8, 512, 0, stream>>>(xs, norm_g + i * 128, norm_b + i * 128, x0, h, n, i);
    }

    k_pool_score<<<(n + 3) / 4, 256, 0, stream>>>(h, pa_w1, pa_b1, pa_w2, pa_b2, score, n);
    k_softmax_reduce<<<1, 256, 0, stream>>>(score, stats, gf, n);
    k_gf<<<200, 128, 0, stream>>>(h, score, stats, gf, n);
    k_head<<<1, 128, 0, stream>>>(gf, tf, task_w, task_b, task_g, task_be,
                                  v_w1, v_b1, v_g, v_be, v_w2, v_b2,
                                  a_w1, a_b1, a_g, a_be, a_w2, a_b2,
                                  (float*)d_out);
}

// Round 6
// 798.127 us; speedup vs baseline: 2.1847x; 1.0067x over previous
//
#include <hip/hip_runtime.h>
#include <math.h>

#define NN 25000
#define EE 400000
#define LL 3
#define LNEPS 1e-5f
#define EB 64

typedef __attribute__((ext_vector_type(8))) short short8;
typedef __attribute__((ext_vector_type(16))) float f32x16;

__device__ __forceinline__ float lrelu(float x, float s) { return fmaxf(x, x * s); }

__device__ __forceinline__ unsigned int pack_bf2(float lo, float hi) {
    unsigned int ul = __float_as_uint(lo), uh = __float_as_uint(hi);
    ul = (ul + 0x7FFFu + ((ul >> 16) & 1u)) >> 16;
    uh = (uh + 0x7FFFu + ((uh >> 16) & 1u)) >> 16;
    return (uh << 16) | (ul & 0xFFFFu);
}
__device__ __forceinline__ float bf_lo(unsigned int u) { return __uint_as_float(u << 16); }
__device__ __forceinline__ float bf_hi(unsigned int u) { return __uint_as_float(u & 0xFFFF0000u); }

// 128-thread block LN stats (2 waves)
__device__ __forceinline__ void ln_stats128(float v, float* red, float& mean, float& inv) {
    float sm = v, sq = v * v;
#pragma unroll
    for (int m = 32; m >= 1; m >>= 1) { sm += __shfl_xor(sm, m); sq += __shfl_xor(sq, m); }
    __syncthreads();
    if ((threadIdx.x & 63) == 0) { red[(threadIdx.x >> 6) * 2] = sm; red[(threadIdx.x >> 6) * 2 + 1] = sq; }
    __syncthreads();
    sm = red[0] + red[2]; sq = red[1] + red[3];
    mean = sm * (1.f / 128.f);
    float var = sq * (1.f / 128.f) - mean * mean;
    inv = rsqrtf(var + LNEPS);
}

// ================= edge sorting (counting sort by dst) =================
__global__ void k_hist(const int* __restrict__ dst, int* __restrict__ cnt, int ne)
{
    int i = blockIdx.x * 256 + threadIdx.x;
    if (i < ne) atomicAdd(&cnt[dst[i]], 1);
}

__global__ __launch_bounds__(1024) void k_scan(const int* __restrict__ cnt,
                                               int* __restrict__ starts, int n)
{
    __shared__ int tot[1024];
    int t = threadIdx.x;
    const int PER = (n + 1023) >> 10;
    int i0 = t * PER;
    int s = 0;
    for (int k = 0; k < PER; ++k) { int i = i0 + k; s += (i < n) ? cnt[i] : 0; }
    tot[t] = s;
    __syncthreads();
    for (int off = 1; off < 1024; off <<= 1) {
        int x = (t >= off) ? tot[t - off] : 0;
        __syncthreads();
        tot[t] += x;
        __syncthreads();
    }
    int run = (t > 0) ? tot[t - 1] : 0;
    for (int k = 0; k < PER; ++k) {
        int i = i0 + k;
        if (i < n) { starts[i] = run; run += cnt[i]; }
    }
    if (t == 1023) starts[n] = tot[1023];
}

__global__ void k_scatter(const int* __restrict__ src, const int* __restrict__ dst,
                          const float* __restrict__ ea, int* __restrict__ cursor,
                          int* __restrict__ s_src, int* __restrict__ s_dst,
                          float* __restrict__ s_ea, int ne)
{
    int i = blockIdx.x * 256 + threadIdx.x;
    if (i >= ne) return;
    int d = dst[i];
    int pos = atomicAdd(&cursor[d], 1);
    s_src[pos] = src[i];
    s_dst[pos] = d;
    s_ea[pos] = ea[i];
}

// ================= weight pre-pack: fp32 [128x128] -> bf16 B-fragment order ====
// mat m: 0..2 gat_w[i]; 3..8 ec_w1 layer (m-3)>>1 half (m-3)&1; 9..11 ec_w2[i]; 12 emb_w
__global__ void k_prep(const float* __restrict__ gat_w, const float* __restrict__ ec_w1,
                       const float* __restrict__ ec_w2, const float* __restrict__ emb_w,
                       uint4* __restrict__ wf)
{
    int g = blockIdx.x * 256 + threadIdx.x;   // < 13*2048
    int m = g >> 11, f = g & 2047;
    const float* srcm;
    if (m < 3) srcm = gat_w + (size_t)m * 16384;
    else if (m < 9) { int t2 = m - 3; srcm = ec_w1 + (size_t)(t2 >> 1) * 32768 + (size_t)(t2 & 1) * 16384; }
    else if (m < 12) srcm = ec_w2 + (size_t)(m - 9) * 16384;
    else srcm = emb_w;
    int l = f & 63, ks = (f >> 6) & 7, nb = f >> 9;
    int k0 = ks * 16 + (l >> 5) * 8, col = nb * 32 + (l & 31);
    const float* wp = srcm + (size_t)k0 * 128 + col;
    uint4 r;
    r.x = pack_bf2(wp[0],   wp[128]);
    r.y = pack_bf2(wp[256], wp[384]);
    r.z = pack_bf2(wp[512], wp[640]);
    r.w = pack_bf2(wp[768], wp[896]);
    wf[g] = r;
}

// ---- MFMA embedding: h = x0 = lrelu(LN(x @ emb_w + emb_b)) ----
__global__ __launch_bounds__(256) void k_emb(
    const float* __restrict__ in, const uint4* __restrict__ wfm,
    const float* __restrict__ bias, const float* __restrict__ g,
    const float* __restrict__ be, float* __restrict__ h,
    float* __restrict__ x0, int nrows)
{
    __shared__ __align__(16) unsigned int sA[64 * 64];
    __shared__ __align__(16) unsigned int sW[2048 * 4];   // 32KB, reused as sU
    float* sU = (float*)sW;
    const int tid = threadIdx.x;
    const int r0 = blockIdx.x * 64;
    {
        int row = tid >> 2, q = tid & 3;
        const float* srcp = in + (size_t)(r0 + row) * 128 + q * 32;
        bool ok = (r0 + row) < nrows;
#pragma unroll
        for (int i = 0; i < 8; ++i) {
            float4 v = ok ? *(const float4*)&srcp[i * 4] : make_float4(0.f, 0.f, 0.f, 0.f);
            int cu = (q * 16 + i * 2) ^ ((row & 15) << 2);
            *(uint2*)&sA[row * 64 + cu] = make_uint2(pack_bf2(v.x, v.y), pack_bf2(v.z, v.w));
        }
    }
    {
        uint4* sW4 = (uint4*)sW;
#pragma unroll
        for (int i = 0; i < 8; ++i) sW4[tid + 256 * i] = wfm[tid + 256 * i];
    }
    __syncthreads();
    const int w = tid >> 6, l = tid & 63;
    const int m0 = (w >> 1) * 32, nhalf = (w & 1);
    f32x16 acc0 = {}, acc1 = {};
#pragma unroll
    for (int ks = 0; ks < 8; ++ks) {
        int rw = m0 + (l & 31);
        int cu = (ks * 8 + (l >> 5) * 4) ^ ((rw & 15) << 2);
        short8 a = *(const short8*)&sA[rw * 64 + cu];
        short8 b0 = *(const short8*)&sW[((nhalf * 16 + ks) * 64 + l) * 4];
        short8 b1 = *(const short8*)&sW[(((nhalf * 2 + 1) * 8 + ks) * 64 + l) * 4];
        acc0 = __builtin_amdgcn_mfma_f32_32x32x16_bf16(a, b0, acc0, 0, 0, 0);
        acc1 = __builtin_amdgcn_mfma_f32_32x32x16_bf16(a, b1, acc1, 0, 0, 0);
    }
    __syncthreads();   // all waves done reading sW
    {
        int colbase = nhalf * 64 + (l & 31);
        float bb0 = bias[colbase], bb1 = bias[colbase + 32];
#pragma unroll
        for (int r = 0; r < 16; ++r) {
            int rw = m0 + (r & 3) + 8 * (r >> 2) + 4 * (l >> 5);
            sU[rw * 128 + colbase]      = acc0[r] + bb0;
            sU[rw * 128 + colbase + 32] = acc1[r] + bb1;
        }
    }
    __syncthreads();
    // LN epilogue: 4 waves x 16 rows
    float2 gv = *(const float2*)&g[l * 2];
    float2 bv = *(const float2*)&be[l * 2];
    for (int it = 0; it < 16; ++it) {
        int rw = w * 16 + it;
        int grow = r0 + rw;
        if (grow >= nrows) break;
        float2 v = *(const float2*)&sU[rw * 128 + l * 2];
        float sm = v.x + v.y, sq = v.x * v.x + v.y * v.y;
#pragma unroll
        for (int m = 32; m >= 1; m >>= 1) { sm += __shfl_xor(sm, m); sq += __shfl_xor(sq, m); }
        float mean = sm * (1.f / 128.f);
        float var = sq * (1.f / 128.f) - mean * mean;
        float inv = rsqrtf(var + LNEPS);
        float o0 = lrelu((v.x - mean) * inv * gv.x + bv.x, 0.01f);
        float o1 = lrelu((v.y - mean) * inv * gv.y + bv.y, 0.01f);
        unsigned off = (unsigned)grow * 128u + (unsigned)(l * 2);
        *(float2*)&h[off]  = make_float2(o0, o1);
        *(float2*)&x0[off] = make_float2(o0, o1);
    }
}

// ---- MFMA 3-in-1 node GEMM: {ht, A'(+b1), B} = h @ {Wht, WA, WB}, packed bf16 out ----
__global__ __launch_bounds__(256) void k_gemm3(
    const float* __restrict__ in, const uint4* __restrict__ wf,
    int mht, int mA, int mB, const float* __restrict__ bA,
    unsigned* __restrict__ o0, unsigned* __restrict__ o1, unsigned* __restrict__ o2,
    int nrows)
{
    __shared__ __align__(16) unsigned int sA[64 * 64];     // 16KB bf16 tile, XOR-swizzled
    __shared__ __align__(16) unsigned int sW[2048 * 4];    // 32KB B-fragments
    const int tid = threadIdx.x;
    const int r0 = blockIdx.x * 64;
    {
        int row = tid >> 2, q = tid & 3;
        const float* srcp = in + (size_t)(r0 + row) * 128 + q * 32;
        bool ok = (r0 + row) < nrows;
#pragma unroll
        for (int i = 0; i < 8; ++i) {
            float4 v = ok ? *(const float4*)&srcp[i * 4] : make_float4(0.f, 0.f, 0.f, 0.f);
            unsigned int p0 = pack_bf2(v.x, v.y), p1 = pack_bf2(v.z, v.w);
            int cu = (q * 16 + i * 2) ^ ((row & 15) << 2);
            *(uint2*)&sA[row * 64 + cu] = make_uint2(p0, p1);
        }
    }
    __syncthreads();
    const int w = tid >> 6, l = tid & 63;
    const int m0 = (w >> 1) * 32, nhalf = (w & 1);
    short8 af[8];
#pragma unroll
    for (int ks = 0; ks < 8; ++ks) {
        int row = m0 + (l & 31);
        int cu = (ks * 8 + (l >> 5) * 4) ^ ((row & 15) << 2);
        af[ks] = *(const short8*)&sA[row * 64 + cu];
    }
    const int c = l & 31;
    const bool evenl = (c & 1) == 0;
    const unsigned uidx = (unsigned)(nhalf * 32 + (evenl ? (c >> 1) : (16 + (c >> 1))));
    auto do_mat = [&](int mat, unsigned* out, const float* bp) {
        __syncthreads();
        {
            const uint4* wsrc = wf + (size_t)mat * 2048;
            uint4* sW4 = (uint4*)sW;
#pragma unroll
            for (int i = 0; i < 8; ++i) sW4[tid + 256 * i] = wsrc[tid + 256 * i];
        }
        __syncthreads();
        f32x16 acc0 = {}, acc1 = {};
        const int nb0 = nhalf * 2;
#pragma unroll
        for (int ks = 0; ks < 8; ++ks) {
            short8 b0 = *(const short8*)&sW[((nb0 * 8 + ks) * 64 + l) * 4];
            short8 b1v = *(const short8*)&sW[(((nb0 + 1) * 8 + ks) * 64 + l) * 4];
            acc0 = __builtin_amdgcn_mfma_f32_32x32x16_bf16(af[ks], b0, acc0, 0, 0, 0);
            acc1 = __builtin_amdgcn_mfma_f32_32x32x16_bf16(af[ks], b1v, acc1, 0, 0, 0);
        }
        int colbase = nhalf * 64 + c;
        float badd0 = bp ? bp[colbase] : 0.f;
        float badd1 = bp ? bp[colbase + 32] : 0.f;
#pragma unroll
        for (int r = 0; r < 16; ++r) {
            float v0 = acc0[r] + badd0;
            float v1 = acc1[r] + badd1;
            float v0p = __shfl_xor(v0, 1);
            float v1p = __shfl_xor(v1, 1);
            int row = r0 + m0 + (r & 3) + 8 * (r >> 2) + 4 * (l >> 5);
            if (row < nrows) {
                unsigned val = evenl ? pack_bf2(v0, v0p) : pack_bf2(v1p, v1);
                out[(unsigned)row * 64u + uidx] = val;
            }
        }
    };
    do_mat(mht, o0, nullptr);
    do_mat(mA, o1, bA);
    do_mat(mB, o2, nullptr);
}

// ---- merged per-node pass: GAT scores + selfe/denom init + row sums of A',B ----
__global__ __launch_bounds__(512) void k_node_scores(
    const unsigned* __restrict__ htp, const unsigned* __restrict__ Apk,
    const unsigned* __restrict__ Bpk,
    const float* __restrict__ as_, const float* __restrict__ ad_,
    float* __restrict__ a_s, float* __restrict__ a_d,
    float* __restrict__ denom, float* __restrict__ selfe,
    float* __restrict__ rsA, float* __restrict__ rsB, int n)
{
    int wv = threadIdx.x >> 6, ln = threadIdx.x & 63;
    int node = blockIdx.x * 8 + wv;
    if (node >= n) return;
    unsigned off = (unsigned)node * 64u + (unsigned)ln;
    unsigned hv = htp[off], av = Apk[off], bv = Bpk[off];
    float h0 = bf_lo(hv), h1 = bf_hi(hv);
    float2 wsv = *(const float2*)&as_[ln * 2];
    float2 wdv = *(const float2*)&ad_[ln * 2];
    float ss = h0 * wsv.x + h1 * wsv.y;
    float sd = h0 * wdv.x + h1 * wdv.y;
    float sa = bf_lo(av) + bf_hi(av), sb = bf_lo(bv) + bf_hi(bv);
#pragma unroll
    for (int m = 16; m >= 1; m >>= 1) {
        ss += __shfl_xor(ss, m); sd += __shfl_xor(sd, m);
        sa += __shfl_xor(sa, m); sb += __shfl_xor(sb, m);
    }
    float sa2 = sa + __shfl_xor(sa, 32);
    float sb2 = sb + __shfl_xor(sb, 32);
    if ((ln & 31) == 0) {
        int hd = ln >> 5;
        a_s[node * 2 + hd] = ss;
        a_d[node * 2 + hd] = sd;
        float ev = expf(lrelu(ss + sd, 0.2f));
        denom[node * 2 + hd] = ev;
        selfe[node * 2 + hd] = ev;
        if (hd == 0) { rsA[node] = sa2; rsB[node] = sb2; }
    }
}

// ---- accumulate exp(e) per dst over sorted edges, run-merged ----
__global__ void k_edge_denom2(const int* __restrict__ s_src, const int* __restrict__ s_dst,
                              const float* __restrict__ a_s, const float* __restrict__ a_d,
                              float* __restrict__ denom, int ne)
{
    int base = (blockIdx.x * 256 + threadIdx.x) * 8;
    if (base >= ne) return;
    int curd = -1;
    float acc0 = 0.f, acc1 = 0.f;
    for (int k = 0; k < 8; ++k) {
        int e = base + k;
        if (e >= ne) break;
        int s = s_src[e], d = s_dst[e];
        float v0 = expf(lrelu(a_s[(unsigned)(s * 2)]     + a_d[(unsigned)(d * 2)],     0.2f));
        float v1 = expf(lrelu(a_s[(unsigned)(s * 2 + 1)] + a_d[(unsigned)(d * 2 + 1)], 0.2f));
        if (d != curd) {
            if (curd >= 0) { atomicAdd(&denom[curd * 2], acc0); atomicAdd(&denom[curd * 2 + 1], acc1); }
            curd = d; acc0 = v0; acc1 = v1;
        } else { acc0 += v0; acc1 += v1; }
    }
    if (curd >= 0) { atomicAdd(&denom[curd * 2], acc0); atomicAdd(&denom[curd * 2 + 1], acc1); }
}

// ---- xsum = gat_bias + self-loop GAT contribution (packed ht) ----
__global__ void k_xsum_init(const unsigned* __restrict__ htp, const float* __restrict__ selfe,
                            const float* __restrict__ denom,
                            const float* __restrict__ gbias, float* __restrict__ xsum, int n)
{
    unsigned idx = blockIdx.x * blockDim.x + threadIdx.x;
    if (idx >= (unsigned)n * 64u) return;
    unsigned node = idx >> 6, u = idx & 63, hd = u >> 5;
    float alpha = selfe[node * 2 + hd] / denom[node * 2 + hd];
    unsigned hv = htp[idx];
    float2 o;
    o.x = gbias[u * 2]     + bf_lo(hv) * alpha;
    o.y = gbias[u * 2 + 1] + bf_hi(hv) * alpha;
    *(float2*)&xsum[node * 128u + u * 2u] = o;
}

// ---- fused edge kernel (dst-sorted): EdgeConv MLP (MFMA) + GAT, run-merged scatter ----
__global__ __launch_bounds__(512) void k_edge_main(
    const unsigned* __restrict__ Apk, const unsigned* __restrict__ Bpk,
    const unsigned* __restrict__ htp,
    const int* __restrict__ s_src, const int* __restrict__ s_dst,
    const float* __restrict__ s_ea,
    const float* __restrict__ a_s, const float* __restrict__ a_d,
    const float* __restrict__ denom,
    const uint4* __restrict__ w2f,
    const float* __restrict__ rsA, const float* __restrict__ rsB,
    const float* __restrict__ g1, const float* __restrict__ be1,
    const float* __restrict__ b2, const float* __restrict__ g2, const float* __restrict__ be2,
    float* __restrict__ xsum, int ne)
{
    // sWB: W2 bf16 B-fragments (32KB); reused after phase 2 as fp32 sU[64][128].
    __shared__ __align__(16) unsigned int sWB[2048 * 4];
    __shared__ __align__(16) unsigned int sT32[EB * 64];   // t tile bf16 pairs, XOR-swizzled
    __shared__ int   sS[EB], sD[EB];
    __shared__ float sEA[EB], sM[EB];
    __shared__ float sAl[EB * 2];
    __shared__ float sG1[128], sE1[128], sB2[128], sG2[128], sE2[128];
    float* sU = (float*)sWB;

    const int tid = threadIdx.x;
    {   // stage W2 fragments: pure copy (pre-packed by k_prep)
        uint4* sWB4 = (uint4*)sWB;
#pragma unroll
        for (int i = 0; i < 4; ++i) { int f = tid + 512 * i; sWB4[f] = w2f[f]; }
    }
    if (tid < 128) {
        sG1[tid] = g1[tid]; sE1[tid] = be1[tid];
        sB2[tid] = b2[tid]; sG2[tid] = g2[tid]; sE2[tid] = be2[tid];
    }
    const int e0 = blockIdx.x * EB;
    const int nev = (ne - e0 < EB) ? (ne - e0) : EB;
    if (tid < EB) {
        if (tid < nev) {
            int s = s_src[e0 + tid], d = s_dst[e0 + tid];
            sS[tid] = s; sD[tid] = d; sEA[tid] = s_ea[e0 + tid];
            sM[tid] = (rsA[s] + rsB[d]) * (1.f / 128.f);
        } else { sS[tid] = 0; sD[tid] = -1; sEA[tid] = 0.f; sM[tid] = 0.f; }
    }
    if (tid < 2 * EB) {
        int le = tid >> 1, hd = tid & 1;
        float al = 0.f;
        if (le < nev) {
            int e = e0 + le;
            int s = s_src[e], d = s_dst[e];
            float ev = lrelu(a_s[(unsigned)(s * 2 + hd)] + a_d[(unsigned)(d * 2 + hd)], 0.2f);
            al = expf(ev) / denom[(unsigned)(d * 2 + hd)];
        }
        sAl[le * 2 + hd] = al;
    }
    __syncthreads();

    // phase 1: t = lrelu(LN(A'[src]+B[dst]), 0.2) -> bf16 LDS (mean precomputed)
    const int wv = tid >> 6, ln = tid & 63;
    {
        const float g1a = sG1[ln * 2], g1b = sG1[ln * 2 + 1];
        const float e1a = sE1[ln * 2], e1b = sE1[ln * 2 + 1];
        for (int j = 0; j < 8; ++j) {
            int e = wv * 8 + j;
            if (e < nev) {
                unsigned s = (unsigned)sS[e], d = (unsigned)sD[e];
                float mean = sM[e];
                unsigned av = Apk[s * 64u + ln];
                unsigned bv = Bpk[d * 64u + ln];
                float v0 = bf_lo(av) + bf_lo(bv) - mean;
                float v1 = bf_hi(av) + bf_hi(bv) - mean;
                float sq = v0 * v0 + v1 * v1;
#pragma unroll
                for (int m = 32; m >= 1; m >>= 1) sq += __shfl_xor(sq, m);
                float inv = rsqrtf(sq * (1.f / 128.f) + LNEPS);
                float t0 = lrelu(v0 * inv * g1a + e1a, 0.2f);
                float t1 = lrelu(v1 * inv * g1b + e1b, 0.2f);
                sT32[e * 64 + (ln ^ ((e & 15) << 2))] = pack_bf2(t0, t1);
            }
        }
    }
    __syncthreads();

    // phase 2: u = t @ W2 via MFMA. 8 waves, each one 32x32 output tile.
    {
        const int w = wv, l = ln;
        const int m0 = (w >> 2) * 32, n0 = (w & 3) * 32;
        f32x16 acc = {};
#pragma unroll
        for (int ks = 0; ks < 8; ++ks) {
            int row = m0 + (l & 31);
            int colu = (ks * 8 + (l >> 5) * 4) ^ ((row & 15) << 2);
            short8 a = *(const short8*)&sT32[row * 64 + colu];
            short8 b = *(const short8*)&sWB[((((w & 3) * 8 + ks) * 64 + l)) * 4];
            acc = __builtin_amdgcn_mfma_f32_32x32x16_bf16(a, b, acc, 0, 0, 0);
        }
        __syncthreads();   // all waves done reading sWB before overwriting as sU
        float b2c = sB2[n0 + (l & 31)];
#pragma unroll
        for (int r = 0; r < 16; ++r) {
            int row = m0 + (r & 3) + 8 * (r >> 2) + 4 * (l >> 5);
            sU[row * 128 + n0 + (l & 31)] = acc[r] + b2c;
        }
    }
    __syncthreads();

    // phase 3: LN(u)+lrelu, *edge_attr, + GAT ht[src]*alpha; run-merged atomic scatter
    {
        const unsigned ln2 = (unsigned)(ln * 2);
        const float g2a = sG2[ln * 2], g2b = sG2[ln * 2 + 1];
        const float e2a = sE2[ln * 2], e2b = sE2[ln * 2 + 1];
        int curd = -1;
        float acc0 = 0.f, acc1 = 0.f;
        for (int j = 0; j < 8; ++j) {
            int e = wv * 8 + j;
            if (e >= nev) break;
            unsigned s = (unsigned)sS[e];
            int d = sD[e];
            float2 uv = *(const float2*)&sU[e * 128 + ln * 2];
            float u0 = uv.x, u1 = uv.y;
            float sm = u0 + u1, sq = u0 * u0 + u1 * u1;
#pragma unroll
            for (int m = 32; m >= 1; m >>= 1) { sm += __shfl_xor(sm, m); sq += __shfl_xor(sq, m); }
            float mean = sm * (1.f / 128.f);
            float var = sq * (1.f / 128.f) - mean * mean;
            float inv = rsqrtf(var + LNEPS);
            float eav = sEA[e];
            float v0 = lrelu((u0 - mean) * inv * g2a + e2a, 0.2f) * eav;
            float v1 = lrelu((u1 - mean) * inv * g2b + e2b, 0.2f) * eav;
            float al = sAl[e * 2 + (ln >> 5)];
            unsigned hv = htp[s * 64u + ln];
            v0 += bf_lo(hv) * al;
            v1 += bf_hi(hv) * al;
            if (d != curd) {
                if (curd >= 0) {
                    atomicAdd(&xsum[(unsigned)curd * 128u + ln2], acc0);
                    atomicAdd(&xsum[(unsigned)curd * 128u + ln2 + 1], acc1);
                }
                curd = d; acc0 = v0; acc1 = v1;
            } else { acc0 += v0; acc1 += v1; }
        }
        if (curd >= 0) {
            atomicAdd(&xsum[(unsigned)curd * 128u + ln2], acc0);
            atomicAdd(&xsum[(unsigned)curd * 128u + ln2 + 1], acc1);
        }
    }
}

// ---- h = lrelu(LN(xsum)) (+ x0 residual), wave-per-node ----
__global__ __launch_bounds__(512) void k_norm8(const float* __restrict__ xsum,
                                               const float* __restrict__ g,
                                               const float* __restrict__ b,
                                               float* __restrict__ x0,
                                               float* __restrict__ h, int n, int layer)
{
    int wv = threadIdx.x >> 6, ln = threadIdx.x & 63;
    int node = blockIdx.x * 8 + wv;
    if (node >= n) return;
    unsigned off = (unsigned)node * 128u + (unsigned)(ln * 2);
    float2 v = *(const float2*)&xsum[off];
    float sm = v.x + v.y, sq = v.x * v.x + v.y * v.y;
#pragma unroll
    for (int m = 32; m >= 1; m >>= 1) { sm += __shfl_xor(sm, m); sq += __shfl_xor(sq, m); }
    float mean = sm * (1.f / 128.f);
    float var = sq * (1.f / 128.f) - mean * mean;
    float inv = rsqrtf(var + LNEPS);
    float2 gv = *(const float2*)&g[ln * 2];
    float2 bv = *(const float2*)&b[ln * 2];
    float val0 = lrelu((v.x - mean) * inv * gv.x + bv.x, 0.01f);
    float val1 = lrelu((v.y - mean) * inv * gv.y + bv.y, 0.01f);
    if (layer > 0) {
        float2 x0v = *(const float2*)&x0[off];
        val0 += x0v.x; val1 += x0v.y;
        *(float2*)&x0[off] = make_float2(val0, val1);
    }
    *(float2*)&h[off] = make_float2(val0, val1);
}

// ---- pooling attention scores (one node per wave) ----
__global__ __launch_bounds__(256) void k_pool_score(const float* __restrict__ h,
    const float* __restrict__ w1, const float* __restrict__ b1,
    const float* __restrict__ w2, const float* __restrict__ b2,
    float* __restrict__ score, int n)
{
    int wv = threadIdx.x >> 6, ln = threadIdx.x & 63;
    int node = blockIdx.x * 4 + wv;
    if (node >= n) return;
    float acc = b1[ln];
    const float* hr = h + (size_t)node * 128;
    for (int k = 0; k < 128; ++k) acc += hr[k] * w1[k * 64 + ln];
    acc = lrelu(acc, 0.01f) * w2[ln];
#pragma unroll
    for (int m = 32; m >= 1; m >>= 1) acc += __shfl_xor(acc, m);
    if (ln == 0) score[node] = acc + b2[0];
}

// ---- softmax stats (single block) + zero gf ----
__global__ __launch_bounds__(256) void k_softmax_reduce(const float* __restrict__ score,
                                                        float* __restrict__ stats,
                                                        float* __restrict__ gf, int n)
{
    __shared__ float red[8];
    int t = threadIdx.x;
    float mx = -1e30f;
    for (int i = t; i < n; i += 256) mx = fmaxf(mx, score[i]);
#pragma unroll
    for (int m = 32; m >= 1; m >>= 1) mx = fmaxf(mx, __shfl_xor(mx, m));
    if ((t & 63) == 0) red[t >> 6] = mx;
    __syncthreads();
    mx = fmaxf(fmaxf(red[0], red[1]), fmaxf(red[2], red[3]));
    float s = 0.f;
    for (int i = t; i < n; i += 256) s += expf(score[i] - mx);
#pragma unroll
    for (int m = 32; m >= 1; m >>= 1) s += __shfl_xor(s, m);
    if ((t & 63) == 0) red[4 + (t >> 6)] = s;
    __syncthreads();
    s = red[4] + red[5] + red[6] + red[7];
    if (t == 0) { stats[0] = mx; stats[1] = s; }
    if (t < 128) gf[t] = 0.f;
}

// ---- gf = sum_n softmax(score)[n] * h[n,:] ----
__global__ __launch_bounds__(128) void k_gf(const float* __restrict__ h,
                                            const float* __restrict__ score,
                                            const float* __restrict__ stats,
                                            float* __restrict__ gf, int n)
{
    int c = threadIdx.x;
    float mx = stats[0], invZ = 1.f / stats[1];
    int per = (n + gridDim.x - 1) / gridDim.x;
    int n0 = blockIdx.x * per;
    int n1 = n0 + per; if (n1 > n) n1 = n;
    float acc = 0.f;
    for (int i = n0; i < n1; ++i)
        acc += expf(score[i] - mx) * invZ * h[(size_t)i * 128 + c];
    atomicAdd(&gf[c], acc);
}

// ---- final head (single 128-thread block) ----
__global__ __launch_bounds__(128) void k_head(
    const float* __restrict__ gf, const float* __restrict__ tf,
    const float* __restrict__ task_w, const float* __restrict__ task_b,
    const float* __restrict__ task_g, const float* __restrict__ task_be,
    const float* __restrict__ v_w1, const float* __restrict__ v_b1,
    const float* __restrict__ v_g, const float* __restrict__ v_be,
    const float* __restrict__ v_w2, const float* __restrict__ v_b2,
    const float* __restrict__ a_w1, const float* __restrict__ a_b1,
    const float* __restrict__ a_g, const float* __restrict__ a_be,
    const float* __restrict__ a_w2, const float* __restrict__ a_b2,
    float* __restrict__ out)
{
    __shared__ float cf[256], hbuf[128], red[4], sc[2], adv[10];
    int t = threadIdx.x;
    float mean, inv;
    float te = task_b[t];
#pragma unroll
    for (int k = 0; k < 4; ++k) te += tf[k] * task_w[k * 128 + t];
    ln_stats128(te, red, mean, inv);
    te = lrelu((te - mean) * inv * task_g[t] + task_be[t], 0.01f);
    cf[t] = gf[t]; cf[128 + t] = te;
    __syncthreads();
    float v = v_b1[t];
    for (int k = 0; k < 256; ++k) v += cf[k] * v_w1[k * 128 + t];
    ln_stats128(v, red, mean, inv);
    v = lrelu((v - mean) * inv * v_g[t] + v_be[t], 0.01f);
    float pv = v * v_w2[t];
#pragma unroll
    for (int m = 32; m >= 1; m >>= 1) pv += __shfl_xor(pv, m);
    __syncthreads();
    if ((t & 63) == 0) red[t >> 6] = pv;
    __syncthreads();
    if (t == 0) sc[0] = red[0] + red[1] + v_b2[0];
    float a = a_b1[t];
    for (int k = 0; k < 256; ++k) a += cf[k] * a_w1[k * 128 + t];
    ln_stats128(a, red, mean, inv);
    a = lrelu((a - mean) * inv * a_g[t] + a_be[t], 0.01f);
    hbuf[t] = a;
    __syncthreads();
    if (t < 10) {
        float s = a_b2[t];
        for (int c = 0; c < 128; ++c) s += hbuf[c] * a_w2[c * 10 + t];
        adv[t] = s;
    }
    __syncthreads();
    if (t == 0) {
        float m10 = 0.f;
        for (int o = 0; o < 10; ++o) m10 += adv[o];
        sc[1] = m10 * 0.1f;
    }
    __syncthreads();
    if (t < 10) out[t] = sc[0] + adv[t] - sc[1];
}

extern "C" void kernel_launch(void* const* d_in, const int* in_sizes, int n_in,
                              void* d_out, int out_size, void* d_ws, size_t ws_size,
                              hipStream_t stream)
{
    const float* x        = (const float*)d_in[0];
    const int*   ei       = (const int*)d_in[1];
    const float* ea       = (const float*)d_in[2];
    const float* tf       = (const float*)d_in[3];
    const float* emb_w    = (const float*)d_in[4];
    const float* emb_b    = (const float*)d_in[5];
    const float* emb_g    = (const float*)d_in[6];
    const float* emb_beta = (const float*)d_in[7];
    const float* gat_w    = (const float*)d_in[8];
    const float* gat_as   = (const float*)d_in[9];
    const float* gat_ad   = (const float*)d_in[10];
    const float* gat_bias = (const float*)d_in[11];
    const float* ec_w1    = (const float*)d_in[12];
    const float* ec_b1    = (const float*)d_in[13];
    const float* ec_g1    = (const float*)d_in[14];
    const float* ec_be1   = (const float*)d_in[15];
    const float* ec_w2    = (const float*)d_in[16];
    const float* ec_b2    = (const float*)d_in[17];
    const float* ec_g2    = (const float*)d_in[18];
    const float* ec_be2   = (const float*)d_in[19];
    const float* norm_g   = (const float*)d_in[20];
    const float* norm_b   = (const float*)d_in[21];
    const float* task_w   = (const float*)d_in[22];
    const float* task_b   = (const float*)d_in[23];
    const float* task_g   = (const float*)d_in[24];
    const float* task_be  = (const float*)d_in[25];
    const float* pa_w1    = (const float*)d_in[26];
    const float* pa_b1    = (const float*)d_in[27];
    const float* pa_w2    = (const float*)d_in[28];
    const float* pa_b2    = (const float*)d_in[29];
    const float* v_w1     = (const float*)d_in[30];
    const float* v_b1     = (const float*)d_in[31];
    const float* v_g      = (const float*)d_in[32];
    const float* v_be     = (const float*)d_in[33];
    const float* v_w2     = (const float*)d_in[34];
    const float* v_b2     = (const float*)d_in[35];
    const float* a_w1     = (const float*)d_in[36];
    const float* a_b1     = (const float*)d_in[37];
    const float* a_g      = (const float*)d_in[38];
    const float* a_be     = (const float*)d_in[39];
    const float* a_w2     = (const float*)d_in[40];
    const float* a_b2     = (const float*)d_in[41];

    const int n = in_sizes[0] / 128;   // 25000
    const int e = in_sizes[2];         // 400000
    const int* src = ei;
    const int* dst = ei + e;

    float* ws = (float*)d_ws;
    uint4* wf = (uint4*)ws;                  // 13 * 2048 uint4 = 416KB
    float* base = ws + 13 * 2048 * 4;
    const size_t NR = (size_t)n * 128;
    const size_t NP = (size_t)n * 64;
    float* h    = base;
    float* x0   = base + NR;
    float* xs   = base + 2 * NR;
    unsigned* htp = (unsigned*)(base + 3 * NR);
    unsigned* Apk = htp + NP;
    unsigned* Bpk = Apk + NP;
    float* a_s  = (float*)(Bpk + NP);
    float* a_d  = a_s + (size_t)n * 2;
    float* den  = a_d + (size_t)n * 2;
    float* selfe = den + (size_t)n * 2;
    float* rsA  = selfe + (size_t)n * 2;
    float* rsB  = rsA + n;
    float* score = rsB + n;
    float* stats = score + n;
    float* gf    = stats + 2;
    int*   cnt    = (int*)(gf + 128);
    int*   starts = cnt + n;
    int*   s_src  = starts + (n + 1);
    int*   s_dst  = s_src + e;
    float* s_ea   = (float*)(s_dst + e);

    const int ng64 = (n + 63) / 64;
    const int ng8 = (n + 7) / 8;

    // ---- one-time: counting-sort edges by dst + weight pre-pack ----
    hipMemsetAsync(cnt, 0, (size_t)n * sizeof(int), stream);
    k_hist<<<(e + 255) / 256, 256, 0, stream>>>(dst, cnt, e);
    k_scan<<<1, 1024, 0, stream>>>(cnt, starts, n);
    hipMemcpyAsync(cnt, starts, (size_t)n * sizeof(int), hipMemcpyDeviceToDevice, stream);
    k_scatter<<<(e + 255) / 256, 256, 0, stream>>>(src, dst, ea, cnt, s_src, s_dst, s_ea, e);
    k_prep<<<104, 256, 0, stream>>>(gat_w, ec_w1, ec_w2, emb_w, wf);

    // embedding: h = x0 = lrelu(LN(x @ emb_w + emb_b))
    k_emb<<<ng64, 256, 0, stream>>>(x, wf + (size_t)12 * 2048, emb_b, emb_g, emb_beta, h, x0, n);

    for (int i = 0; i < LL; ++i) {
        k_gemm3<<<ng64, 256, 0, stream>>>(h, wf, i, 3 + 2 * i, 4 + 2 * i,
                                          ec_b1 + i * 128, htp, Apk, Bpk, n);
        k_node_scores<<<ng8, 512, 0, stream>>>(htp, Apk, Bpk, gat_as + i * 128, gat_ad + i * 128,
                                               a_s, a_d, den, selfe, rsA, rsB, n);
        k_edge_denom2<<<((e + 7) / 8 + 255) / 256, 256, 0, stream>>>(s_src, s_dst, a_s, a_d, den, e);
        k_xsum_init<<<(n * 64 + 255) / 256, 256, 0, stream>>>(htp, selfe, den,
                                                              gat_bias + i * 128, xs, n);
        k_edge_main<<<(e + EB - 1) / EB, 512, 0, stream>>>(Apk, Bpk, htp, s_src, s_dst, s_ea,
                                                           a_s, a_d, den,
                                                           wf + (size_t)(9 + i) * 2048,
                                                           rsA, rsB,
                                                           ec_g1 + i * 128, ec_be1 + i * 128,
                                                           ec_b2 + i * 128, ec_g2 + i * 128, ec_be2 + i * 128,
                                                           xs, e);
        k_norm8<<<ng8, 512, 0, stream>>>(xs, norm_g + i * 128, norm_b + i * 128, x0, h, n, i);
    }

    k_pool_score<<<(n + 3) / 4, 256, 0, stream>>>(h, pa_w1, pa_b1, pa_w2, pa_b2, score, n);
    k_softmax_reduce<<<1, 256, 0, stream>>>(score, stats, gf, n);
    k_gf<<<200, 128, 0, stream>>>(h, score, stats, gf, n);
    k_head<<<1, 128, 0, stream>>>(gf, tf, task_w, task_b, task_g, task_be,
                                  v_w1, v_b1, v_g, v_be, v_w2, v_b2,
                                  a_w1, a_b1, a_g, a_be, a_w2, a_b2,
                                  (float*)d_out);
}